// Round 2
// baseline (3028.201 us; speedup 1.0000x reference)
//
#include <hip/hip_runtime.h>
#include <hip/hip_bf16.h>
#include <cstdint>

#define NN 131072      // nodes
#define NE 524288      // directed edges
#define DIM 275        // feature dim
#define DP 288         // padded stride (multiple of 16)
#define NFEAT 9
#define NVOC 128
#define NLAY 5
#define NPG 64
#define NGRAPH 2048
#define BN_EPS 1e-5f

typedef unsigned short u16;

__device__ __forceinline__ float bf2f(u16 u) {
  union { unsigned int i; float f; } x; x.i = ((unsigned int)u) << 16; return x.f;
}
__device__ __forceinline__ u16 f2bf(float f) {
  union { float f; unsigned int i; } x; x.f = f;
  unsigned int r = x.i + 0x7fffu + ((x.i >> 16) & 1u);
  return (u16)(r >> 16);
}

// ---------------- graph preprocessing ----------------

__global__ void hist_kernel(const int* __restrict__ ei, int* __restrict__ cnt) {
  int e = blockIdx.x * 256 + threadIdx.x;
  if (e < NE) atomicAdd(&cnt[ei[NE + e]], 1);
}

__global__ void dinv_kernel(const int* __restrict__ cnt, float* __restrict__ dinv) {
  int v = blockIdx.x * 256 + threadIdx.x;
  if (v < NN) dinv[v] = rsqrtf(1.0f + (float)cnt[v]);   // deg = in-degree + self loop
}

__global__ void scan_block_kernel(const int* __restrict__ in, int* __restrict__ out_ex,
                                  int* __restrict__ partials) {
  __shared__ int buf[2][1024];
  int t = threadIdx.x;
  int idx = blockIdx.x * 1024 + t;
  int v = in[idx];
  buf[0][t] = v;
  __syncthreads();
  int cur = 0;
  for (int off = 1; off < 1024; off <<= 1) {
    int x = buf[cur][t];
    if (t >= off) x += buf[cur][t - off];
    buf[cur ^ 1][t] = x;
    __syncthreads();
    cur ^= 1;
  }
  out_ex[idx] = buf[cur][t] - v;
  if (t == 1023) partials[blockIdx.x] = buf[cur][t];
}

__global__ void scan_partials_kernel(int* partials) {
  __shared__ int buf[2][128];
  int t = threadIdx.x;
  int v = partials[t];
  buf[0][t] = v;
  __syncthreads();
  int cur = 0;
  for (int off = 1; off < 128; off <<= 1) {
    int x = buf[cur][t];
    if (t >= off) x += buf[cur][t - off];
    buf[cur ^ 1][t] = x;
    __syncthreads();
    cur ^= 1;
  }
  partials[t] = buf[cur][t] - v;   // exclusive
}

__global__ void add_offsets_kernel(int* __restrict__ indptr, const int* __restrict__ partials,
                                   int* __restrict__ cursor) {
  int i = blockIdx.x * 256 + threadIdx.x;
  if (i < NN) {
    int v = indptr[i] + partials[i >> 10];
    indptr[i] = v;
    cursor[i] = v;
  }
  if (i == 0) indptr[NN] = NE;
}

__global__ void fill_csr_kernel(const int* __restrict__ ei, int* __restrict__ cursor,
                                int* __restrict__ srcs) {
  int e = blockIdx.x * 256 + threadIdx.x;
  if (e < NE) {
    int c = ei[NE + e];
    int p = atomicAdd(&cursor[c], 1);
    srcs[p] = ei[e];
  }
}

// Pad all 6 weight matrices ([275x275], K-major) into [320][288] zero-filled bf16 tiles.
__global__ void wpad_kernel(const float* __restrict__ convW, const float* __restrict__ postW,
                            u16* __restrict__ Wp) {
  int i = blockIdx.x * 256 + threadIdx.x;
  const int total = 6 * 320 * DP;
  if (i >= total) return;
  int k = i % DP;
  int r = i / DP;
  int j = r % 320;
  int m = r / 320;
  float val = 0.f;
  if (j < DIM && k < DIM)
    val = (m < 5) ? convW[((size_t)m * DIM + j) * DIM + k] : postW[(size_t)j * DIM + k];
  Wp[i] = f2bf(val);
}

// ---------------- atom encoder ----------------

__global__ void embed_kernel(const int* __restrict__ xa, const float* __restrict__ emb,
                             u16* __restrict__ P) {
  int n = blockIdx.x;
  int idx[NFEAT];
#pragma unroll
  for (int f = 0; f < NFEAT; ++f) idx[f] = xa[n * NFEAT + f];
  for (int d = threadIdx.x; d < DP; d += 128) {
    float s = 0.f;
    if (d < DIM) {
#pragma unroll
      for (int f = 0; f < NFEAT; ++f) s += emb[((size_t)f * NVOC + idx[f]) * DIM + d];
    }
    P[(size_t)n * DP + d] = f2bf(s);   // also zeroes pad columns
  }
}

// ---------------- GEMM: C = rowscale .* (act(A) @ W^T) + colbias ----------------
// act(a,k) = relu(a*scale[k]+shift[k]) when scale!=null (BN+ReLU of previous layer).
// A:[NN][DP] bf16, Wp:[320][DP] bf16 (zero-padded), C:[NN][DP] bf16.

__launch_bounds__(256)
__global__ void gemm_kernel(const u16* __restrict__ A, const u16* __restrict__ Wp,
                            u16* __restrict__ C,
                            const float* __restrict__ scale, const float* __restrict__ shift,
                            const float* __restrict__ rowscale, const float* __restrict__ colbias) {
  __shared__ float As[16][68];
  __shared__ float Ws[16][68];
  int t = threadIdx.x;
  int tx = t & 15, ty = t >> 4;
  int row0 = blockIdx.x * 64;
  int col0 = blockIdx.y * 64;
  int lr = t >> 2;           // 0..63
  int lk = (t & 3) << 2;     // 0,4,8,12
  float acc[4][4] = {};
  const u16* Arow = A + (size_t)(row0 + lr) * DP;
  const u16* Wrow = Wp + (size_t)(col0 + lr) * DP;
  for (int k0 = 0; k0 < DP; k0 += 16) {
    uint2 ua = *(const uint2*)(Arow + k0 + lk);
    float a0 = bf2f((u16)ua.x), a1 = bf2f((u16)(ua.x >> 16));
    float a2 = bf2f((u16)ua.y), a3 = bf2f((u16)(ua.y >> 16));
    if (scale) {
      float4 s4 = *(const float4*)(scale + k0 + lk);
      float4 h4 = *(const float4*)(shift + k0 + lk);
      a0 = fmaxf(fmaf(a0, s4.x, h4.x), 0.f);
      a1 = fmaxf(fmaf(a1, s4.y, h4.y), 0.f);
      a2 = fmaxf(fmaf(a2, s4.z, h4.z), 0.f);
      a3 = fmaxf(fmaf(a3, s4.w, h4.w), 0.f);
    }
    uint2 ub = *(const uint2*)(Wrow + k0 + lk);
    As[lk + 0][lr] = a0; As[lk + 1][lr] = a1; As[lk + 2][lr] = a2; As[lk + 3][lr] = a3;
    Ws[lk + 0][lr] = bf2f((u16)ub.x);
    Ws[lk + 1][lr] = bf2f((u16)(ub.x >> 16));
    Ws[lk + 2][lr] = bf2f((u16)ub.y);
    Ws[lk + 3][lr] = bf2f((u16)(ub.y >> 16));
    __syncthreads();
#pragma unroll
    for (int kk = 0; kk < 16; ++kk) {
      float4 av = *(const float4*)&As[kk][ty << 2];
      float4 bv = *(const float4*)&Ws[kk][tx << 2];
      float a_[4] = {av.x, av.y, av.z, av.w};
      float b_[4] = {bv.x, bv.y, bv.z, bv.w};
#pragma unroll
      for (int i = 0; i < 4; ++i)
#pragma unroll
        for (int j = 0; j < 4; ++j) acc[i][j] = fmaf(a_[i], b_[j], acc[i][j]);
    }
    __syncthreads();
  }
#pragma unroll
  for (int i = 0; i < 4; ++i) {
    int gr = row0 + (ty << 2) + i;
    float rs = rowscale ? rowscale[gr] : 1.f;
    u16* Crow = C + (size_t)gr * DP;
#pragma unroll
    for (int j = 0; j < 4; ++j) {
      int gc = col0 + (tx << 2) + j;
      if (gc < DIM)
        Crow[gc] = f2bf(fmaf(acc[i][j], rs, colbias ? colbias[gc] : 0.f));
      else if (gc < DP)
        Crow[gc] = 0;   // keep pad columns zero
    }
  }
}

// ---------------- SpMM aggregate + fused BN-stat partials ----------------
// Y[v] = dinv[v]*(sum_{u in in(v)} X[u] + X[v]) + bias ; accumulate col sums/sumsq.

__launch_bounds__(128)
__global__ void spmm_kernel(const u16* __restrict__ X, u16* __restrict__ Y,
                            const int* __restrict__ indptr, const int* __restrict__ srcs,
                            const float* __restrict__ dinv, const float* __restrict__ bias,
                            float* __restrict__ bn_sum, float* __restrict__ bn_sq) {
  int t = threadIdx.x;
  int v0 = blockIdx.x * 64;
  int d0 = t, d1 = t + 128, d2 = t + 256;
  bool has2 = d2 < DIM;
  float s0 = 0, s1 = 0, s2 = 0, q0 = 0, q1 = 0, q2 = 0;
  for (int v = v0; v < v0 + 64; ++v) {
    int e0 = indptr[v], e1 = indptr[v + 1];
    const u16* xv = X + (size_t)v * DP;
    float a0 = bf2f(xv[d0]), a1 = bf2f(xv[d1]), a2 = has2 ? bf2f(xv[d2]) : 0.f;
    for (int e = e0; e < e1; ++e) {
      const u16* xu = X + (size_t)srcs[e] * DP;
      a0 += bf2f(xu[d0]);
      a1 += bf2f(xu[d1]);
      if (has2) a2 += bf2f(xu[d2]);
    }
    float dv = dinv[v];
    u16* yv = Y + (size_t)v * DP;
    float y0 = fmaf(dv, a0, bias[d0]);
    float y1 = fmaf(dv, a1, bias[d1]);
    yv[d0] = f2bf(y0); yv[d1] = f2bf(y1);
    s0 += y0; q0 += y0 * y0;
    s1 += y1; q1 += y1 * y1;
    if (has2) {
      float y2 = fmaf(dv, a2, bias[d2]);
      yv[d2] = f2bf(y2);
      s2 += y2; q2 += y2 * y2;
    }
  }
  atomicAdd(&bn_sum[d0], s0); atomicAdd(&bn_sq[d0], q0);
  atomicAdd(&bn_sum[d1], s1); atomicAdd(&bn_sq[d1], q1);
  if (has2) { atomicAdd(&bn_sum[d2], s2); atomicAdd(&bn_sq[d2], q2); }
}

__global__ void bn_finalize_kernel(const float* __restrict__ bn_sum, const float* __restrict__ bn_sq,
                                   const float* __restrict__ gamma, const float* __restrict__ beta,
                                   float* __restrict__ scale, float* __restrict__ shift) {
  int d = threadIdx.x;
  if (d >= DP) return;
  if (d < DIM) {
    const float invN = 1.0f / (float)NN;
    float mu = bn_sum[d] * invN;
    float var = bn_sq[d] * invN - mu * mu;
    float rstd = rsqrtf(var + BN_EPS);
    float sc = gamma[d] * rstd;
    scale[d] = sc;
    shift[d] = fmaf(-mu, sc, beta[d]);
  } else {
    scale[d] = 0.f;   // pad: relu(0*x+0)=0 keeps K-loop guard-free
    shift[d] = 0.f;
  }
}

// ---------------- per-graph Gram decode: out[g] = X @ X^T ----------------

__launch_bounds__(256)
__global__ void decode_kernel(const u16* __restrict__ H, float* __restrict__ out) {
  __shared__ float Xs[32][68];
  int g = blockIdx.x;
  int t = threadIdx.x;
  int tx = t & 15, ty = t >> 4;
  int lr = t >> 2;          // 0..63
  int lk = (t & 3) << 3;    // 0,8,16,24
  const u16* Hg = H + (size_t)g * NPG * DP;
  float acc[4][4] = {};
  for (int k0 = 0; k0 < DP; k0 += 32) {
    uint4 u = *(const uint4*)(Hg + (size_t)lr * DP + k0 + lk);
    Xs[lk + 0][lr] = bf2f((u16)u.x); Xs[lk + 1][lr] = bf2f((u16)(u.x >> 16));
    Xs[lk + 2][lr] = bf2f((u16)u.y); Xs[lk + 3][lr] = bf2f((u16)(u.y >> 16));
    Xs[lk + 4][lr] = bf2f((u16)u.z); Xs[lk + 5][lr] = bf2f((u16)(u.z >> 16));
    Xs[lk + 6][lr] = bf2f((u16)u.w); Xs[lk + 7][lr] = bf2f((u16)(u.w >> 16));
    __syncthreads();
#pragma unroll
    for (int kk = 0; kk < 32; ++kk) {
      float4 av = *(const float4*)&Xs[kk][ty << 2];
      float4 bv = *(const float4*)&Xs[kk][tx << 2];
      float a_[4] = {av.x, av.y, av.z, av.w};
      float b_[4] = {bv.x, bv.y, bv.z, bv.w};
#pragma unroll
      for (int i = 0; i < 4; ++i)
#pragma unroll
        for (int j = 0; j < 4; ++j) acc[i][j] = fmaf(a_[i], b_[j], acc[i][j]);
    }
    __syncthreads();
  }
  float* og = out + (size_t)g * NPG * NPG;
#pragma unroll
  for (int i = 0; i < 4; ++i)
#pragma unroll
    for (int j = 0; j < 4; ++j)
      og[((ty << 2) + i) * NPG + (tx << 2) + j] = acc[i][j];
}

// ---------------- launch ----------------

extern "C" void kernel_launch(void* const* d_in, const int* in_sizes, int n_in,
                              void* d_out, int out_size, void* d_ws, size_t ws_size,
                              hipStream_t stream) {
  const int* xa = (const int*)d_in[0];
  const int* ei = (const int*)d_in[1];
  const float* emb = (const float*)d_in[2];
  const float* convW = (const float*)d_in[3];
  const float* convB = (const float*)d_in[4];
  const float* gamma = (const float*)d_in[5];
  const float* beta = (const float*)d_in[6];
  const float* postW = (const float*)d_in[7];
  const float* postB = (const float*)d_in[8];
  float* out = (float*)d_out;

  char* w = (char*)d_ws;
  u16* P = (u16*)w;          w += (size_t)NN * DP * sizeof(u16);
  u16* Q = (u16*)w;          w += (size_t)NN * DP * sizeof(u16);
  u16* Wp = (u16*)w;         w += (size_t)6 * 320 * DP * sizeof(u16);
  float* dinv = (float*)w;   w += (size_t)NN * sizeof(float);
  int* cnt = (int*)w;        w += (size_t)NN * sizeof(int);
  int* indptr = (int*)w;     w += (size_t)(NN + 64) * sizeof(int);
  int* cursor = (int*)w;     w += (size_t)NN * sizeof(int);
  int* srcs = (int*)w;       w += (size_t)NE * sizeof(int);
  int* partials = (int*)w;   w += 256 * sizeof(int);
  float* bn_sum = (float*)w; w += DP * sizeof(float);
  float* bn_sq = (float*)w;  w += DP * sizeof(float);
  float* bnscale = (float*)w; w += DP * sizeof(float);
  float* bnshift = (float*)w; w += DP * sizeof(float);

  // workspace budget check: if insufficient, bail out cleanly (absmax fail,
  // not a memory fault) so the failure mode is diagnostic.
  size_t need = (size_t)(w - (char*)d_ws);
  if (ws_size < need) return;

  // graph structure (recomputed each call; deterministic work)
  hipMemsetAsync(cnt, 0, (size_t)NN * sizeof(int), stream);
  hist_kernel<<<NE / 256, 256, 0, stream>>>(ei, cnt);
  dinv_kernel<<<NN / 256, 256, 0, stream>>>(cnt, dinv);
  scan_block_kernel<<<NN / 1024, 1024, 0, stream>>>(cnt, indptr, partials);
  scan_partials_kernel<<<1, 128, 0, stream>>>(partials);
  add_offsets_kernel<<<NN / 256, 256, 0, stream>>>(indptr, partials, cursor);
  fill_csr_kernel<<<NE / 256, 256, 0, stream>>>(ei, cursor, srcs);
  wpad_kernel<<<(6 * 320 * DP + 255) / 256, 256, 0, stream>>>(convW, postW, Wp);
  embed_kernel<<<NN, 128, 0, stream>>>(xa, emb, P);

  for (int l = 0; l < NLAY; ++l) {
    gemm_kernel<<<dim3(NN / 64, 5), 256, 0, stream>>>(
        P, Wp + (size_t)l * 320 * DP, Q,
        l ? bnscale : nullptr, l ? bnshift : nullptr, dinv, nullptr);
    hipMemsetAsync(bn_sum, 0, 2 * DP * sizeof(float), stream);
    spmm_kernel<<<NN / 64, 128, 0, stream>>>(Q, P, indptr, srcs, dinv,
                                             convB + (size_t)l * DIM, bn_sum, bn_sq);
    bn_finalize_kernel<<<1, DP, 0, stream>>>(bn_sum, bn_sq, gamma + (size_t)l * DIM,
                                             beta + (size_t)l * DIM, bnscale, bnshift);
  }

  // post_mp linear (BN+ReLU of layer 4 fused on load, bias added, no rowscale)
  gemm_kernel<<<dim3(NN / 64, 5), 256, 0, stream>>>(
      P, Wp + (size_t)5 * 320 * DP, Q, bnscale, bnshift, nullptr, postB);

  // pairwise dot-product decode per graph
  decode_kernel<<<NGRAPH, 256, 0, stream>>>(Q, out);
}

// Round 3
// 1341.847 us; speedup vs baseline: 2.2567x; 2.2567x over previous
//
#include <hip/hip_runtime.h>
#include <hip/hip_bf16.h>
#include <cstdint>

#define NN 131072      // nodes
#define NE 524288      // directed edges
#define DIM 275        // feature dim
#define DP 288         // padded stride (multiple of 16)
#define NFEAT 9
#define NVOC 128
#define NLAY 5
#define NPG 64
#define NGRAPH 2048
#define BN_EPS 1e-5f
#define BM 128
#define BN 64
#define BK 32

typedef unsigned short u16;
typedef __attribute__((ext_vector_type(8))) short s16x8;
typedef __attribute__((ext_vector_type(4))) float f32x4;

__device__ __forceinline__ float bf2f(u16 u) {
  union { unsigned int i; float f; } x; x.i = ((unsigned int)u) << 16; return x.f;
}
__device__ __forceinline__ u16 f2bf(float f) {
  union { float f; unsigned int i; } x; x.f = f;
  unsigned int r = x.i + 0x7fffu + ((x.i >> 16) & 1u);
  return (u16)(r >> 16);
}

// ---------------- graph preprocessing ----------------

__global__ void hist_kernel(const int* __restrict__ ei, int* __restrict__ cnt) {
  int e = blockIdx.x * 256 + threadIdx.x;
  if (e < NE) atomicAdd(&cnt[ei[NE + e]], 1);
}

__global__ void dinv_kernel(const int* __restrict__ cnt, float* __restrict__ dinv) {
  int v = blockIdx.x * 256 + threadIdx.x;
  if (v < NN) dinv[v] = rsqrtf(1.0f + (float)cnt[v]);
}

__global__ void scan_block_kernel(const int* __restrict__ in, int* __restrict__ out_ex,
                                  int* __restrict__ partials) {
  __shared__ int buf[2][1024];
  int t = threadIdx.x;
  int idx = blockIdx.x * 1024 + t;
  int v = in[idx];
  buf[0][t] = v;
  __syncthreads();
  int cur = 0;
  for (int off = 1; off < 1024; off <<= 1) {
    int x = buf[cur][t];
    if (t >= off) x += buf[cur][t - off];
    buf[cur ^ 1][t] = x;
    __syncthreads();
    cur ^= 1;
  }
  out_ex[idx] = buf[cur][t] - v;
  if (t == 1023) partials[blockIdx.x] = buf[cur][t];
}

__global__ void scan_partials_kernel(int* partials) {
  __shared__ int buf[2][128];
  int t = threadIdx.x;
  int v = partials[t];
  buf[0][t] = v;
  __syncthreads();
  int cur = 0;
  for (int off = 1; off < 128; off <<= 1) {
    int x = buf[cur][t];
    if (t >= off) x += buf[cur][t - off];
    buf[cur ^ 1][t] = x;
    __syncthreads();
    cur ^= 1;
  }
  partials[t] = buf[cur][t] - v;
}

__global__ void add_offsets_kernel(int* __restrict__ indptr, const int* __restrict__ partials,
                                   int* __restrict__ cursor) {
  int i = blockIdx.x * 256 + threadIdx.x;
  if (i < NN) {
    int v = indptr[i] + partials[i >> 10];
    indptr[i] = v;
    cursor[i] = v;
  }
  if (i == 0) indptr[NN] = NE;
}

__global__ void fill_csr_kernel(const int* __restrict__ ei, int* __restrict__ cursor,
                                int* __restrict__ srcs) {
  int e = blockIdx.x * 256 + threadIdx.x;
  if (e < NE) {
    int c = ei[NE + e];
    int p = atomicAdd(&cursor[c], 1);
    srcs[p] = ei[e];
  }
}

__global__ void wpad_kernel(const float* __restrict__ convW, const float* __restrict__ postW,
                            u16* __restrict__ Wp) {
  int i = blockIdx.x * 256 + threadIdx.x;
  const int total = 6 * 320 * DP;
  if (i >= total) return;
  int k = i % DP;
  int r = i / DP;
  int j = r % 320;
  int m = r / 320;
  float val = 0.f;
  if (j < DIM && k < DIM)
    val = (m < 5) ? convW[((size_t)m * DIM + j) * DIM + k] : postW[(size_t)j * DIM + k];
  Wp[i] = f2bf(val);
}

// ---------------- atom encoder ----------------

__global__ void embed_kernel(const int* __restrict__ xa, const float* __restrict__ emb,
                             u16* __restrict__ P) {
  int n = blockIdx.x;
  int idx[NFEAT];
#pragma unroll
  for (int f = 0; f < NFEAT; ++f) idx[f] = xa[n * NFEAT + f];
  for (int d = threadIdx.x; d < DP; d += 128) {
    float s = 0.f;
    if (d < DIM) {
#pragma unroll
      for (int f = 0; f < NFEAT; ++f) s += emb[((size_t)f * NVOC + idx[f]) * DIM + d];
    }
    P[(size_t)n * DP + d] = f2bf(s);
  }
}

// ---------------- MFMA GEMM ----------------
// C = rowscale .* (act(A) @ W^T) + colbias, act = relu(x*scale+shift) if scale.
// A:[NN][DP] bf16, Wp:[320][DP] bf16 zero-padded, C:[NN][DP] bf16 (pads zeroed).

__device__ __forceinline__ uint4 xform8(uint4 r, const float* __restrict__ sc,
                                        const float* __restrict__ sh, int k) {
  union { uint4 u; u16 h[8]; } in, out;
  in.u = r;
#pragma unroll
  for (int j = 0; j < 8; ++j) {
    float x = fmaf(bf2f(in.h[j]), sc[k + j], sh[k + j]);
    out.h[j] = f2bf(fmaxf(x, 0.f));
  }
  return out.u;
}

__launch_bounds__(256)
__global__ void gemm_kernel(const u16* __restrict__ A, const u16* __restrict__ Wp,
                            u16* __restrict__ C,
                            const float* __restrict__ scale, const float* __restrict__ shift,
                            const float* __restrict__ rowscale, const float* __restrict__ colbias) {
  __shared__ __align__(16) u16 Asl[2][BM * BK];
  __shared__ __align__(16) u16 Bsl[2][BN * BK];
  const int tid = threadIdx.x;
  const int lane = tid & 63;
  const int wv = tid >> 6, wm = wv & 1, wn = wv >> 1;
  const int row0 = blockIdx.x * BM, col0 = blockIdx.y * BN;

  // staging: thread covers (row=tid>>2, 16B slot=tid&3); XOR-swizzled slot in LDS
  const int sr = tid >> 2, ssl = tid & 3;
  const int swz = ((ssl ^ (sr & 3) ^ ((sr >> 2) & 3)) << 3);
  const int aw0 = sr * BK + swz;
  const int aw1 = aw0 + 64 * BK;
  const int bw = sr * BK + swz;
  const u16* ag0 = A + (size_t)(row0 + sr) * DP + ssl * 8;
  const u16* ag1 = A + (size_t)(row0 + 64 + sr) * DP + ssl * 8;
  const u16* bg = Wp + (size_t)(col0 + sr) * DP + ssl * 8;

  // fragment read offsets (same swizzle)
  const int fr = lane & 15, fs = lane >> 4;
  const int fswz = ((fs ^ (fr & 3) ^ ((fr >> 2) & 3)) << 3);
  int aoff[4], boff[2];
#pragma unroll
  for (int i = 0; i < 4; ++i) aoff[i] = (wm * 64 + i * 16 + fr) * BK + fswz;
#pragma unroll
  for (int i = 0; i < 2; ++i) boff[i] = (wn * 32 + i * 16 + fr) * BK + fswz;

  const bool bn = (scale != nullptr);

  // prologue: stage k-step 0
  uint4 ra0 = *(const uint4*)(ag0);
  uint4 ra1 = *(const uint4*)(ag1);
  uint4 rb = *(const uint4*)(bg);
  if (bn) {
    ra0 = xform8(ra0, scale, shift, ssl * 8);
    ra1 = xform8(ra1, scale, shift, ssl * 8);
  }
  *(uint4*)&Asl[0][aw0] = ra0;
  *(uint4*)&Asl[0][aw1] = ra1;
  *(uint4*)&Bsl[0][bw] = rb;
  __syncthreads();

  f32x4 acc[4][2];
#pragma unroll
  for (int i = 0; i < 4; ++i)
#pragma unroll
    for (int j = 0; j < 2; ++j) acc[i][j] = (f32x4){0.f, 0.f, 0.f, 0.f};

  for (int s = 0; s < DP / BK; ++s) {
    const int cur = s & 1;
    uint4 na0, na1, nb;
    const bool more = (s < DP / BK - 1);
    if (more) {  // issue next-tile loads early; latency hides under MFMA
      na0 = *(const uint4*)(ag0 + (s + 1) * BK);
      na1 = *(const uint4*)(ag1 + (s + 1) * BK);
      nb = *(const uint4*)(bg + (s + 1) * BK);
    }
    s16x8 af[4], bf[2];
#pragma unroll
    for (int i = 0; i < 4; ++i) af[i] = *(const s16x8*)&Asl[cur][aoff[i]];
#pragma unroll
    for (int i = 0; i < 2; ++i) bf[i] = *(const s16x8*)&Bsl[cur][boff[i]];
#pragma unroll
    for (int i = 0; i < 4; ++i)
#pragma unroll
      for (int j = 0; j < 2; ++j)
        acc[i][j] = __builtin_amdgcn_mfma_f32_16x16x32_bf16(af[i], bf[j], acc[i][j], 0, 0, 0);
    if (more) {
      int k2 = (s + 1) * BK + ssl * 8;
      if (bn) {
        na0 = xform8(na0, scale, shift, k2);
        na1 = xform8(na1, scale, shift, k2);
      }
      *(uint4*)&Asl[cur ^ 1][aw0] = na0;
      *(uint4*)&Asl[cur ^ 1][aw1] = na1;
      *(uint4*)&Bsl[cur ^ 1][bw] = nb;
    }
    __syncthreads();
  }

  // epilogue: D row = (lane>>4)*4+r (A side), col = lane&15 (B side)
#pragma unroll
  for (int i = 0; i < 4; ++i) {
    int gr0 = row0 + wm * 64 + i * 16 + fs * 4;
    float rs[4];
#pragma unroll
    for (int r = 0; r < 4; ++r) rs[r] = rowscale ? rowscale[gr0 + r] : 1.f;
#pragma unroll
    for (int j = 0; j < 2; ++j) {
      int gc = col0 + wn * 32 + j * 16 + fr;
      if (gc < DP) {
        float cb = (colbias && gc < DIM) ? colbias[gc] : 0.f;
#pragma unroll
        for (int r = 0; r < 4; ++r) {
          u16 o = (gc < DIM) ? f2bf(fmaf(acc[i][j][r], rs[r], cb)) : (u16)0;
          C[(size_t)(gr0 + r) * DP + gc] = o;
        }
      }
    }
  }
}

// ---------------- SpMM aggregate + fused BN-stat partials ----------------
// wave-per-node-group: 4 waves/block, 16 nodes/wave; lane covers 4 cols via uint2.

__launch_bounds__(256)
__global__ void spmm_kernel(const u16* __restrict__ X, u16* __restrict__ Y,
                            const int* __restrict__ indptr, const int* __restrict__ srcs,
                            const float* __restrict__ dinv, const float* __restrict__ bias,
                            float* __restrict__ bn_sum, float* __restrict__ bn_sq) {
  __shared__ float ls[DP], lq[DP];
  int tid = threadIdx.x;
  for (int i = tid; i < DP; i += 256) { ls[i] = 0.f; lq[i] = 0.f; }
  __syncthreads();
  int lane = tid & 63, wv = tid >> 6;
  int vbase = blockIdx.x * 64 + wv * 16;
  int c0 = lane << 2;
  int c1 = 256 + (lane << 2);
  bool tl = lane < 8;
  float bia[4], bib[4];
#pragma unroll
  for (int j = 0; j < 4; ++j) bia[j] = bias[c0 + j];
#pragma unroll
  for (int j = 0; j < 4; ++j) bib[j] = (tl && c1 + j < DIM) ? bias[c1 + j] : 0.f;
  float s0[4] = {}, q0[4] = {}, s1[4] = {}, q1[4] = {};
  for (int v = vbase; v < vbase + 16; ++v) {
    const u16* xv = X + (size_t)v * DP;
    uint2 m = *(const uint2*)(xv + c0);
    float a[4] = {bf2f((u16)m.x), bf2f((u16)(m.x >> 16)), bf2f((u16)m.y), bf2f((u16)(m.y >> 16))};
    float b[4] = {0.f, 0.f, 0.f, 0.f};
    if (tl) {
      uint2 t = *(const uint2*)(xv + c1);
      b[0] = bf2f((u16)t.x); b[1] = bf2f((u16)(t.x >> 16));
      b[2] = bf2f((u16)t.y); b[3] = bf2f((u16)(t.y >> 16));
    }
    int e0 = indptr[v], e1 = indptr[v + 1];
    for (int e = e0; e < e1; ++e) {
      const u16* xu = X + (size_t)srcs[e] * DP;
      uint2 mu = *(const uint2*)(xu + c0);
      a[0] += bf2f((u16)mu.x); a[1] += bf2f((u16)(mu.x >> 16));
      a[2] += bf2f((u16)mu.y); a[3] += bf2f((u16)(mu.y >> 16));
      if (tl) {
        uint2 tu = *(const uint2*)(xu + c1);
        b[0] += bf2f((u16)tu.x); b[1] += bf2f((u16)(tu.x >> 16));
        b[2] += bf2f((u16)tu.y); b[3] += bf2f((u16)(tu.y >> 16));
      }
    }
    float dv = dinv[v];
    u16* yv = Y + (size_t)v * DP;
    float y[4];
#pragma unroll
    for (int j = 0; j < 4; ++j) {
      y[j] = fmaf(dv, a[j], bia[j]);
      s0[j] += y[j]; q0[j] += y[j] * y[j];
    }
    uint2 w;
    w.x = (unsigned)f2bf(y[0]) | ((unsigned)f2bf(y[1]) << 16);
    w.y = (unsigned)f2bf(y[2]) | ((unsigned)f2bf(y[3]) << 16);
    *(uint2*)(yv + c0) = w;
    if (tl) {
      float z[4];
#pragma unroll
      for (int j = 0; j < 4; ++j) {
        z[j] = fmaf(dv, b[j], bib[j]);
        s1[j] += z[j]; q1[j] += z[j] * z[j];
      }
      uint2 w2;
      w2.x = (unsigned)f2bf(z[0]) | ((unsigned)f2bf(z[1]) << 16);
      w2.y = (unsigned)f2bf(z[2]) | ((unsigned)f2bf(z[3]) << 16);
      *(uint2*)(yv + c1) = w2;
    }
  }
#pragma unroll
  for (int j = 0; j < 4; ++j) { atomicAdd(&ls[c0 + j], s0[j]); atomicAdd(&lq[c0 + j], q0[j]); }
  if (tl) {
#pragma unroll
    for (int j = 0; j < 4; ++j) { atomicAdd(&ls[c1 + j], s1[j]); atomicAdd(&lq[c1 + j], q1[j]); }
  }
  __syncthreads();
  for (int i = tid; i < DP; i += 256) {
    atomicAdd(&bn_sum[i], ls[i]);
    atomicAdd(&bn_sq[i], lq[i]);
  }
}

__global__ void bn_finalize_kernel(const float* __restrict__ bn_sum, const float* __restrict__ bn_sq,
                                   const float* __restrict__ gamma, const float* __restrict__ beta,
                                   float* __restrict__ scale, float* __restrict__ shift) {
  int d = threadIdx.x;
  if (d >= DP) return;
  if (d < DIM) {
    const float invN = 1.0f / (float)NN;
    float mu = bn_sum[d] * invN;
    float var = bn_sq[d] * invN - mu * mu;
    float rstd = rsqrtf(var + BN_EPS);
    float sc = gamma[d] * rstd;
    scale[d] = sc;
    shift[d] = fmaf(-mu, sc, beta[d]);
  } else {
    scale[d] = 0.f;
    shift[d] = 0.f;
  }
}

// ---------------- MFMA Gram decode: out[g] = X @ X^T, wave-private LDS ----------------

__launch_bounds__(256)
__global__ void decode_kernel(const u16* __restrict__ H, float* __restrict__ out) {
  __shared__ __align__(16) u16 tile[4][2][NPG * BK];
  int tid = threadIdx.x, lane = tid & 63, wv = tid >> 6;
  int g = blockIdx.x * 4 + wv;
  const u16* Hg = H + (size_t)g * NPG * DP;
  const int ssl = lane & 3;
  int soff[4];
  const u16* sg[4];
#pragma unroll
  for (int i = 0; i < 4; ++i) {
    int r = (lane >> 2) + i * 16;
    soff[i] = r * BK + ((ssl ^ (r & 3) ^ ((r >> 2) & 3)) << 3);
    sg[i] = Hg + (size_t)r * DP + ssl * 8;
  }
  const int fr = lane & 15, fs = lane >> 4;
  const int fswz = ((fs ^ (fr & 3) ^ ((fr >> 2) & 3)) << 3);
  int foff[4];
#pragma unroll
  for (int i = 0; i < 4; ++i) foff[i] = (i * 16 + fr) * BK + fswz;

  u16* t0 = tile[wv][0];
  u16* t1 = tile[wv][1];
  uint4 rg[4];
#pragma unroll
  for (int i = 0; i < 4; ++i) rg[i] = *(const uint4*)(sg[i]);
#pragma unroll
  for (int i = 0; i < 4; ++i) *(uint4*)&t0[soff[i]] = rg[i];

  f32x4 acc[4][4];
#pragma unroll
  for (int i = 0; i < 4; ++i)
#pragma unroll
    for (int j = 0; j < 4; ++j) acc[i][j] = (f32x4){0.f, 0.f, 0.f, 0.f};

  for (int s = 0; s < DP / BK; ++s) {
    u16* cur = (s & 1) ? t1 : t0;
    u16* nxt = (s & 1) ? t0 : t1;
    const bool more = (s < DP / BK - 1);
    if (more) {
#pragma unroll
      for (int i = 0; i < 4; ++i) rg[i] = *(const uint4*)(sg[i] + (s + 1) * BK);
    }
    s16x8 af[4];
#pragma unroll
    for (int i = 0; i < 4; ++i) af[i] = *(const s16x8*)&cur[foff[i]];
#pragma unroll
    for (int i = 0; i < 4; ++i)
#pragma unroll
      for (int j = 0; j < 4; ++j)
        acc[i][j] = __builtin_amdgcn_mfma_f32_16x16x32_bf16(af[i], af[j], acc[i][j], 0, 0, 0);
    if (more) {
#pragma unroll
      for (int i = 0; i < 4; ++i) *(uint4*)&nxt[soff[i]] = rg[i];
    }
  }
  float* og = out + (size_t)g * NPG * NPG;
#pragma unroll
  for (int i = 0; i < 4; ++i) {
    int m0 = i * 16 + fs * 4;
#pragma unroll
    for (int j = 0; j < 4; ++j) {
      int n = j * 16 + fr;
#pragma unroll
      for (int r = 0; r < 4; ++r) og[(m0 + r) * NPG + n] = acc[i][j][r];
    }
  }
}

// ---------------- launch ----------------

extern "C" void kernel_launch(void* const* d_in, const int* in_sizes, int n_in,
                              void* d_out, int out_size, void* d_ws, size_t ws_size,
                              hipStream_t stream) {
  const int* xa = (const int*)d_in[0];
  const int* ei = (const int*)d_in[1];
  const float* emb = (const float*)d_in[2];
  const float* convW = (const float*)d_in[3];
  const float* convB = (const float*)d_in[4];
  const float* gamma = (const float*)d_in[5];
  const float* beta = (const float*)d_in[6];
  const float* postW = (const float*)d_in[7];
  const float* postB = (const float*)d_in[8];
  float* out = (float*)d_out;

  char* w = (char*)d_ws;
  u16* P = (u16*)w;          w += (size_t)NN * DP * sizeof(u16);
  u16* Q = (u16*)w;          w += (size_t)NN * DP * sizeof(u16);
  u16* Wp = (u16*)w;         w += (size_t)6 * 320 * DP * sizeof(u16);
  float* dinv = (float*)w;   w += (size_t)NN * sizeof(float);
  int* cnt = (int*)w;        w += (size_t)NN * sizeof(int);
  int* indptr = (int*)w;     w += (size_t)(NN + 64) * sizeof(int);
  int* cursor = (int*)w;     w += (size_t)NN * sizeof(int);
  int* srcs = (int*)w;       w += (size_t)NE * sizeof(int);
  int* partials = (int*)w;   w += 256 * sizeof(int);
  float* bn_sum = (float*)w; w += DP * sizeof(float);
  float* bn_sq = (float*)w;  w += DP * sizeof(float);
  float* bnscale = (float*)w; w += DP * sizeof(float);
  float* bnshift = (float*)w; w += DP * sizeof(float);

  size_t need = (size_t)(w - (char*)d_ws);
  if (ws_size < need) return;

  hipMemsetAsync(cnt, 0, (size_t)NN * sizeof(int), stream);
  hist_kernel<<<NE / 256, 256, 0, stream>>>(ei, cnt);
  dinv_kernel<<<NN / 256, 256, 0, stream>>>(cnt, dinv);
  scan_block_kernel<<<NN / 1024, 1024, 0, stream>>>(cnt, indptr, partials);
  scan_partials_kernel<<<1, 128, 0, stream>>>(partials);
  add_offsets_kernel<<<NN / 256, 256, 0, stream>>>(indptr, partials, cursor);
  fill_csr_kernel<<<NE / 256, 256, 0, stream>>>(ei, cursor, srcs);
  wpad_kernel<<<(6 * 320 * DP + 255) / 256, 256, 0, stream>>>(convW, postW, Wp);
  embed_kernel<<<NN, 128, 0, stream>>>(xa, emb, P);

  for (int l = 0; l < NLAY; ++l) {
    gemm_kernel<<<dim3(NN / BM, 5), 256, 0, stream>>>(
        P, Wp + (size_t)l * 320 * DP, Q,
        l ? bnscale : nullptr, l ? bnshift : nullptr, dinv, nullptr);
    hipMemsetAsync(bn_sum, 0, 2 * DP * sizeof(float), stream);
    spmm_kernel<<<NN / 64, 256, 0, stream>>>(Q, P, indptr, srcs, dinv,
                                             convB + (size_t)l * DIM, bn_sum, bn_sq);
    bn_finalize_kernel<<<1, DP, 0, stream>>>(bn_sum, bn_sq, gamma + (size_t)l * DIM,
                                             beta + (size_t)l * DIM, bnscale, bnshift);
  }

  gemm_kernel<<<dim3(NN / BM, 5), 256, 0, stream>>>(
      P, Wp + (size_t)5 * 320 * DP, Q, bnscale, bnshift, nullptr, postB);

  decode_kernel<<<NGRAPH / 4, 256, 0, stream>>>(Q, out);
}

// Round 4
// 1304.944 us; speedup vs baseline: 2.3206x; 1.0283x over previous
//
#include <hip/hip_runtime.h>
#include <hip/hip_bf16.h>
#include <cstdint>

#define NN 131072      // nodes
#define NE 524288      // directed edges
#define DIM 275        // feature dim
#define DP 288         // padded stride (multiple of 16)
#define NFEAT 9
#define NVOC 128
#define NLAY 5
#define NPG 64
#define NGRAPH 2048
#define BN_EPS 1e-5f
#define BM 128
#define BN 64
#define BK 32

typedef unsigned short u16;
typedef __attribute__((ext_vector_type(8))) short s16x8;
typedef __attribute__((ext_vector_type(4))) float f32x4;

__device__ __forceinline__ float bf2f(u16 u) {
  union { unsigned int i; float f; } x; x.i = ((unsigned int)u) << 16; return x.f;
}
__device__ __forceinline__ u16 f2bf(float f) {
  union { float f; unsigned int i; } x; x.f = f;
  unsigned int r = x.i + 0x7fffu + ((x.i >> 16) & 1u);
  return (u16)(r >> 16);
}

// ---------------- graph preprocessing ----------------

__global__ void hist_kernel(const int* __restrict__ ei, int* __restrict__ cnt) {
  int e = blockIdx.x * 256 + threadIdx.x;
  if (e < NE) atomicAdd(&cnt[ei[NE + e]], 1);
}

__global__ void dinv_kernel(const int* __restrict__ cnt, float* __restrict__ dinv) {
  int v = blockIdx.x * 256 + threadIdx.x;
  if (v < NN) dinv[v] = rsqrtf(1.0f + (float)cnt[v]);
}

__global__ void scan_block_kernel(const int* __restrict__ in, int* __restrict__ out_ex,
                                  int* __restrict__ partials) {
  __shared__ int buf[2][1024];
  int t = threadIdx.x;
  int idx = blockIdx.x * 1024 + t;
  int v = in[idx];
  buf[0][t] = v;
  __syncthreads();
  int cur = 0;
  for (int off = 1; off < 1024; off <<= 1) {
    int x = buf[cur][t];
    if (t >= off) x += buf[cur][t - off];
    buf[cur ^ 1][t] = x;
    __syncthreads();
    cur ^= 1;
  }
  out_ex[idx] = buf[cur][t] - v;
  if (t == 1023) partials[blockIdx.x] = buf[cur][t];
}

__global__ void scan_partials_kernel(int* partials) {
  __shared__ int buf[2][128];
  int t = threadIdx.x;
  int v = partials[t];
  buf[0][t] = v;
  __syncthreads();
  int cur = 0;
  for (int off = 1; off < 128; off <<= 1) {
    int x = buf[cur][t];
    if (t >= off) x += buf[cur][t - off];
    buf[cur ^ 1][t] = x;
    __syncthreads();
    cur ^= 1;
  }
  partials[t] = buf[cur][t] - v;
}

__global__ void add_offsets_kernel(int* __restrict__ indptr, const int* __restrict__ partials,
                                   int* __restrict__ cursor) {
  int i = blockIdx.x * 256 + threadIdx.x;
  if (i < NN) {
    int v = indptr[i] + partials[i >> 10];
    indptr[i] = v;
    cursor[i] = v;
  }
  if (i == 0) indptr[NN] = NE;
}

__global__ void fill_csr_kernel(const int* __restrict__ ei, int* __restrict__ cursor,
                                int* __restrict__ srcs) {
  int e = blockIdx.x * 256 + threadIdx.x;
  if (e < NE) {
    int c = ei[NE + e];
    int p = atomicAdd(&cursor[c], 1);
    srcs[p] = ei[e];
  }
}

__global__ void wpad_kernel(const float* __restrict__ convW, const float* __restrict__ postW,
                            u16* __restrict__ Wp) {
  int i = blockIdx.x * 256 + threadIdx.x;
  const int total = 6 * 320 * DP;
  if (i >= total) return;
  int k = i % DP;
  int r = i / DP;
  int j = r % 320;
  int m = r / 320;
  float val = 0.f;
  if (j < DIM && k < DIM)
    val = (m < 5) ? convW[((size_t)m * DIM + j) * DIM + k] : postW[(size_t)j * DIM + k];
  Wp[i] = f2bf(val);
}

// ---------------- atom encoder ----------------

__global__ void embed_kernel(const int* __restrict__ xa, const float* __restrict__ emb,
                             u16* __restrict__ P) {
  int n = blockIdx.x;
  int idx[NFEAT];
#pragma unroll
  for (int f = 0; f < NFEAT; ++f) idx[f] = xa[n * NFEAT + f];
  for (int d = threadIdx.x; d < DP; d += 128) {
    float s = 0.f;
    if (d < DIM) {
#pragma unroll
      for (int f = 0; f < NFEAT; ++f) s += emb[((size_t)f * NVOC + idx[f]) * DIM + d];
    }
    P[(size_t)n * DP + d] = f2bf(s);
  }
}

// ---------------- MFMA GEMM ----------------
// C = rowscale .* (act(A) @ W^T) + colbias, act = relu(x*scale+shift) if scale.
// Grid: 1D, 5120 blocks; b = grp*40 + col*8 + x  keeps all 5 col-blocks of a
// row panel on one XCD (b%8 invariant) and dispatch-adjacent -> A panel L2-hit.

__device__ __forceinline__ uint4 xform8(uint4 r, const float* __restrict__ sc,
                                        const float* __restrict__ sh, int k) {
  union { uint4 u; u16 h[8]; } in, out;
  in.u = r;
#pragma unroll
  for (int j = 0; j < 8; ++j) {
    float x = fmaf(bf2f(in.h[j]), sc[k + j], sh[k + j]);
    out.h[j] = f2bf(fmaxf(x, 0.f));
  }
  return out.u;
}

__launch_bounds__(256)
__global__ void gemm_kernel(const u16* __restrict__ A, const u16* __restrict__ Wp,
                            u16* __restrict__ C,
                            const float* __restrict__ scale, const float* __restrict__ shift,
                            const float* __restrict__ rowscale, const float* __restrict__ colbias) {
  __shared__ __align__(16) u16 Asl[2][BM * BK];
  __shared__ __align__(16) u16 Bsl[2][BN * BK];
  const int tid = threadIdx.x;
  const int lane = tid & 63;
  const int wv = tid >> 6, wm = wv & 1, wn = wv >> 1;
  // XCD-pinned block remap
  const int b = blockIdx.x;
  const int grp = b / 40, rem = b % 40;
  const int col = rem >> 3, pan8 = rem & 7;
  const int panel = grp * 8 + pan8;
  const int row0 = panel * BM, col0 = col * BN;

  const int sr = tid >> 2, ssl = tid & 3;
  const int swz = ((ssl ^ (sr & 3) ^ ((sr >> 2) & 3)) << 3);
  const int aw0 = sr * BK + swz;
  const int aw1 = aw0 + 64 * BK;
  const int bw = sr * BK + swz;
  const u16* ag0 = A + (size_t)(row0 + sr) * DP + ssl * 8;
  const u16* ag1 = A + (size_t)(row0 + 64 + sr) * DP + ssl * 8;
  const u16* bg = Wp + (size_t)(col0 + sr) * DP + ssl * 8;

  const int fr = lane & 15, fs = lane >> 4;
  const int fswz = ((fs ^ (fr & 3) ^ ((fr >> 2) & 3)) << 3);
  int aoff[4], boff[2];
#pragma unroll
  for (int i = 0; i < 4; ++i) aoff[i] = (wm * 64 + i * 16 + fr) * BK + fswz;
#pragma unroll
  for (int i = 0; i < 2; ++i) boff[i] = (wn * 32 + i * 16 + fr) * BK + fswz;

  const bool bn = (scale != nullptr);

  uint4 ra0 = *(const uint4*)(ag0);
  uint4 ra1 = *(const uint4*)(ag1);
  uint4 rb = *(const uint4*)(bg);
  if (bn) {
    ra0 = xform8(ra0, scale, shift, ssl * 8);
    ra1 = xform8(ra1, scale, shift, ssl * 8);
  }
  *(uint4*)&Asl[0][aw0] = ra0;
  *(uint4*)&Asl[0][aw1] = ra1;
  *(uint4*)&Bsl[0][bw] = rb;
  __syncthreads();

  f32x4 acc[4][2];
#pragma unroll
  for (int i = 0; i < 4; ++i)
#pragma unroll
    for (int j = 0; j < 2; ++j) acc[i][j] = (f32x4){0.f, 0.f, 0.f, 0.f};

  for (int s = 0; s < DP / BK; ++s) {
    const int cur = s & 1;
    uint4 na0, na1, nb;
    const bool more = (s < DP / BK - 1);
    if (more) {
      na0 = *(const uint4*)(ag0 + (s + 1) * BK);
      na1 = *(const uint4*)(ag1 + (s + 1) * BK);
      nb = *(const uint4*)(bg + (s + 1) * BK);
    }
    s16x8 af[4], bf[2];
#pragma unroll
    for (int i = 0; i < 4; ++i) af[i] = *(const s16x8*)&Asl[cur][aoff[i]];
#pragma unroll
    for (int i = 0; i < 2; ++i) bf[i] = *(const s16x8*)&Bsl[cur][boff[i]];
#pragma unroll
    for (int i = 0; i < 4; ++i)
#pragma unroll
      for (int j = 0; j < 2; ++j)
        acc[i][j] = __builtin_amdgcn_mfma_f32_16x16x32_bf16(af[i], bf[j], acc[i][j], 0, 0, 0);
    if (more) {
      int k2 = (s + 1) * BK + ssl * 8;
      if (bn) {
        na0 = xform8(na0, scale, shift, k2);
        na1 = xform8(na1, scale, shift, k2);
      }
      *(uint4*)&Asl[cur ^ 1][aw0] = na0;
      *(uint4*)&Asl[cur ^ 1][aw1] = na1;
      *(uint4*)&Bsl[cur ^ 1][bw] = nb;
    }
    __syncthreads();
  }

#pragma unroll
  for (int i = 0; i < 4; ++i) {
    int gr0 = row0 + wm * 64 + i * 16 + fs * 4;
    float rs[4];
#pragma unroll
    for (int r = 0; r < 4; ++r) rs[r] = rowscale ? rowscale[gr0 + r] : 1.f;
#pragma unroll
    for (int j = 0; j < 2; ++j) {
      int gc = col0 + wn * 32 + j * 16 + fr;
      if (gc < DP) {
        float cb = (colbias && gc < DIM) ? colbias[gc] : 0.f;
#pragma unroll
        for (int r = 0; r < 4; ++r) {
          u16 o = (gc < DIM) ? f2bf(fmaf(acc[i][j][r], rs[r], cb)) : (u16)0;
          C[(size_t)(gr0 + r) * DP + gc] = o;
        }
      }
    }
  }
}

// ---------------- SpMM aggregate + fused BN-stat partials ----------------
// wave-per-node-group, 4-wide edge unroll for memory-level parallelism.

__launch_bounds__(256)
__global__ void spmm_kernel(const u16* __restrict__ X, u16* __restrict__ Y,
                            const int* __restrict__ indptr, const int* __restrict__ srcs,
                            const float* __restrict__ dinv, const float* __restrict__ bias,
                            float* __restrict__ bn_sum, float* __restrict__ bn_sq) {
  __shared__ float ls[DP], lq[DP];
  int tid = threadIdx.x;
  for (int i = tid; i < DP; i += 256) { ls[i] = 0.f; lq[i] = 0.f; }
  __syncthreads();
  int lane = tid & 63, wv = tid >> 6;
  int vbase = blockIdx.x * 64 + wv * 16;
  int c0 = lane << 2;
  int c1 = 256 + (lane << 2);
  bool tl = lane < 8;
  float bia[4], bib[4];
#pragma unroll
  for (int j = 0; j < 4; ++j) bia[j] = bias[c0 + j];
#pragma unroll
  for (int j = 0; j < 4; ++j) bib[j] = (tl && c1 + j < DIM) ? bias[c1 + j] : 0.f;
  float s0[4] = {}, q0[4] = {}, s1[4] = {}, q1[4] = {};
  for (int v = vbase; v < vbase + 16; ++v) {
    const u16* xv = X + (size_t)v * DP;
    uint2 m = *(const uint2*)(xv + c0);
    float a[4] = {bf2f((u16)m.x), bf2f((u16)(m.x >> 16)), bf2f((u16)m.y), bf2f((u16)(m.y >> 16))};
    float b[4] = {0.f, 0.f, 0.f, 0.f};
    if (tl) {
      uint2 t = *(const uint2*)(xv + c1);
      b[0] = bf2f((u16)t.x); b[1] = bf2f((u16)(t.x >> 16));
      b[2] = bf2f((u16)t.y); b[3] = bf2f((u16)(t.y >> 16));
    }
    int e0 = indptr[v], e1 = indptr[v + 1];
    int e = e0;
    // 4-wide unrolled gather: 4 independent row loads in flight per lane
    for (; e + 4 <= e1; e += 4) {
      int i0 = srcs[e], i1 = srcs[e + 1], i2 = srcs[e + 2], i3 = srcs[e + 3];
      const u16* x0 = X + (size_t)i0 * DP;
      const u16* x1 = X + (size_t)i1 * DP;
      const u16* x2 = X + (size_t)i2 * DP;
      const u16* x3 = X + (size_t)i3 * DP;
      uint2 m0 = *(const uint2*)(x0 + c0);
      uint2 m1 = *(const uint2*)(x1 + c0);
      uint2 m2 = *(const uint2*)(x2 + c0);
      uint2 m3 = *(const uint2*)(x3 + c0);
      uint2 t0, t1, t2, t3;
      if (tl) {
        t0 = *(const uint2*)(x0 + c1);
        t1 = *(const uint2*)(x1 + c1);
        t2 = *(const uint2*)(x2 + c1);
        t3 = *(const uint2*)(x3 + c1);
      }
      a[0] += bf2f((u16)m0.x) + bf2f((u16)m1.x) + bf2f((u16)m2.x) + bf2f((u16)m3.x);
      a[1] += bf2f((u16)(m0.x >> 16)) + bf2f((u16)(m1.x >> 16)) + bf2f((u16)(m2.x >> 16)) + bf2f((u16)(m3.x >> 16));
      a[2] += bf2f((u16)m0.y) + bf2f((u16)m1.y) + bf2f((u16)m2.y) + bf2f((u16)m3.y);
      a[3] += bf2f((u16)(m0.y >> 16)) + bf2f((u16)(m1.y >> 16)) + bf2f((u16)(m2.y >> 16)) + bf2f((u16)(m3.y >> 16));
      if (tl) {
        b[0] += bf2f((u16)t0.x) + bf2f((u16)t1.x) + bf2f((u16)t2.x) + bf2f((u16)t3.x);
        b[1] += bf2f((u16)(t0.x >> 16)) + bf2f((u16)(t1.x >> 16)) + bf2f((u16)(t2.x >> 16)) + bf2f((u16)(t3.x >> 16));
        b[2] += bf2f((u16)t0.y) + bf2f((u16)t1.y) + bf2f((u16)t2.y) + bf2f((u16)t3.y);
        b[3] += bf2f((u16)(t0.y >> 16)) + bf2f((u16)(t1.y >> 16)) + bf2f((u16)(t2.y >> 16)) + bf2f((u16)(t3.y >> 16));
      }
    }
    for (; e < e1; ++e) {
      const u16* xu = X + (size_t)srcs[e] * DP;
      uint2 mu = *(const uint2*)(xu + c0);
      a[0] += bf2f((u16)mu.x); a[1] += bf2f((u16)(mu.x >> 16));
      a[2] += bf2f((u16)mu.y); a[3] += bf2f((u16)(mu.y >> 16));
      if (tl) {
        uint2 tu = *(const uint2*)(xu + c1);
        b[0] += bf2f((u16)tu.x); b[1] += bf2f((u16)(tu.x >> 16));
        b[2] += bf2f((u16)tu.y); b[3] += bf2f((u16)(tu.y >> 16));
      }
    }
    float dv = dinv[v];
    u16* yv = Y + (size_t)v * DP;
    float y[4];
#pragma unroll
    for (int j = 0; j < 4; ++j) {
      y[j] = fmaf(dv, a[j], bia[j]);
      s0[j] += y[j]; q0[j] += y[j] * y[j];
    }
    uint2 w;
    w.x = (unsigned)f2bf(y[0]) | ((unsigned)f2bf(y[1]) << 16);
    w.y = (unsigned)f2bf(y[2]) | ((unsigned)f2bf(y[3]) << 16);
    *(uint2*)(yv + c0) = w;
    if (tl) {
      float z[4];
#pragma unroll
      for (int j = 0; j < 4; ++j) {
        z[j] = fmaf(dv, b[j], bib[j]);
        s1[j] += z[j]; q1[j] += z[j] * z[j];
      }
      uint2 w2;
      w2.x = (unsigned)f2bf(z[0]) | ((unsigned)f2bf(z[1]) << 16);
      w2.y = (unsigned)f2bf(z[2]) | ((unsigned)f2bf(z[3]) << 16);
      *(uint2*)(yv + c1) = w2;
    }
  }
#pragma unroll
  for (int j = 0; j < 4; ++j) { atomicAdd(&ls[c0 + j], s0[j]); atomicAdd(&lq[c0 + j], q0[j]); }
  if (tl) {
#pragma unroll
    for (int j = 0; j < 4; ++j) { atomicAdd(&ls[c1 + j], s1[j]); atomicAdd(&lq[c1 + j], q1[j]); }
  }
  __syncthreads();
  for (int i = tid; i < DP; i += 256) {
    atomicAdd(&bn_sum[i], ls[i]);
    atomicAdd(&bn_sq[i], lq[i]);
  }
}

__global__ void bn_finalize_kernel(const float* __restrict__ bn_sum, const float* __restrict__ bn_sq,
                                   const float* __restrict__ gamma, const float* __restrict__ beta,
                                   float* __restrict__ scale, float* __restrict__ shift) {
  int d = threadIdx.x;
  if (d >= DP) return;
  if (d < DIM) {
    const float invN = 1.0f / (float)NN;
    float mu = bn_sum[d] * invN;
    float var = bn_sq[d] * invN - mu * mu;
    float rstd = rsqrtf(var + BN_EPS);
    float sc = gamma[d] * rstd;
    scale[d] = sc;
    shift[d] = fmaf(-mu, sc, beta[d]);
  } else {
    scale[d] = 0.f;
    shift[d] = 0.f;
  }
}

// ---------------- MFMA Gram decode ----------------

__launch_bounds__(256)
__global__ void decode_kernel(const u16* __restrict__ H, float* __restrict__ out) {
  __shared__ __align__(16) u16 tile[4][2][NPG * BK];
  int tid = threadIdx.x, lane = tid & 63, wv = tid >> 6;
  int g = blockIdx.x * 4 + wv;
  const u16* Hg = H + (size_t)g * NPG * DP;
  const int ssl = lane & 3;
  int soff[4];
  const u16* sg[4];
#pragma unroll
  for (int i = 0; i < 4; ++i) {
    int r = (lane >> 2) + i * 16;
    soff[i] = r * BK + ((ssl ^ (r & 3) ^ ((r >> 2) & 3)) << 3);
    sg[i] = Hg + (size_t)r * DP + ssl * 8;
  }
  const int fr = lane & 15, fs = lane >> 4;
  const int fswz = ((fs ^ (fr & 3) ^ ((fr >> 2) & 3)) << 3);
  int foff[4];
#pragma unroll
  for (int i = 0; i < 4; ++i) foff[i] = (i * 16 + fr) * BK + fswz;

  u16* t0 = tile[wv][0];
  u16* t1 = tile[wv][1];
  uint4 rg[4];
#pragma unroll
  for (int i = 0; i < 4; ++i) rg[i] = *(const uint4*)(sg[i]);
#pragma unroll
  for (int i = 0; i < 4; ++i) *(uint4*)&t0[soff[i]] = rg[i];

  f32x4 acc[4][4];
#pragma unroll
  for (int i = 0; i < 4; ++i)
#pragma unroll
    for (int j = 0; j < 4; ++j) acc[i][j] = (f32x4){0.f, 0.f, 0.f, 0.f};

  for (int s = 0; s < DP / BK; ++s) {
    u16* cur = (s & 1) ? t1 : t0;
    u16* nxt = (s & 1) ? t0 : t1;
    const bool more = (s < DP / BK - 1);
    if (more) {
#pragma unroll
      for (int i = 0; i < 4; ++i) rg[i] = *(const uint4*)(sg[i] + (s + 1) * BK);
    }
    s16x8 af[4];
#pragma unroll
    for (int i = 0; i < 4; ++i) af[i] = *(const s16x8*)&cur[foff[i]];
#pragma unroll
    for (int i = 0; i < 4; ++i)
#pragma unroll
      for (int j = 0; j < 4; ++j)
        acc[i][j] = __builtin_amdgcn_mfma_f32_16x16x32_bf16(af[i], af[j], acc[i][j], 0, 0, 0);
    if (more) {
#pragma unroll
      for (int i = 0; i < 4; ++i) *(uint4*)&nxt[soff[i]] = rg[i];
    }
  }
  float* og = out + (size_t)g * NPG * NPG;
#pragma unroll
  for (int i = 0; i < 4; ++i) {
    int m0 = i * 16 + fs * 4;
#pragma unroll
    for (int j = 0; j < 4; ++j) {
      int n = j * 16 + fr;
#pragma unroll
      for (int r = 0; r < 4; ++r) og[(m0 + r) * NPG + n] = acc[i][j][r];
    }
  }
}

// ---------------- launch ----------------

extern "C" void kernel_launch(void* const* d_in, const int* in_sizes, int n_in,
                              void* d_out, int out_size, void* d_ws, size_t ws_size,
                              hipStream_t stream) {
  const int* xa = (const int*)d_in[0];
  const int* ei = (const int*)d_in[1];
  const float* emb = (const float*)d_in[2];
  const float* convW = (const float*)d_in[3];
  const float* convB = (const float*)d_in[4];
  const float* gamma = (const float*)d_in[5];
  const float* beta = (const float*)d_in[6];
  const float* postW = (const float*)d_in[7];
  const float* postB = (const float*)d_in[8];
  float* out = (float*)d_out;

  char* w = (char*)d_ws;
  u16* P = (u16*)w;          w += (size_t)NN * DP * sizeof(u16);
  u16* Q = (u16*)w;          w += (size_t)NN * DP * sizeof(u16);
  u16* Wp = (u16*)w;         w += (size_t)6 * 320 * DP * sizeof(u16);
  float* dinv = (float*)w;   w += (size_t)NN * sizeof(float);
  int* cnt = (int*)w;        w += (size_t)NN * sizeof(int);
  int* indptr = (int*)w;     w += (size_t)(NN + 64) * sizeof(int);
  int* cursor = (int*)w;     w += (size_t)NN * sizeof(int);
  int* srcs = (int*)w;       w += (size_t)NE * sizeof(int);
  int* partials = (int*)w;   w += 256 * sizeof(int);
  float* bn_sum = (float*)w; w += DP * sizeof(float);
  float* bn_sq = (float*)w;  w += DP * sizeof(float);
  float* bnscale = (float*)w; w += DP * sizeof(float);
  float* bnshift = (float*)w; w += DP * sizeof(float);

  size_t need = (size_t)(w - (char*)d_ws);
  if (ws_size < need) return;

  hipMemsetAsync(cnt, 0, (size_t)NN * sizeof(int), stream);
  hist_kernel<<<NE / 256, 256, 0, stream>>>(ei, cnt);
  dinv_kernel<<<NN / 256, 256, 0, stream>>>(cnt, dinv);
  scan_block_kernel<<<NN / 1024, 1024, 0, stream>>>(cnt, indptr, partials);
  scan_partials_kernel<<<1, 128, 0, stream>>>(partials);
  add_offsets_kernel<<<NN / 256, 256, 0, stream>>>(indptr, partials, cursor);
  fill_csr_kernel<<<NE / 256, 256, 0, stream>>>(ei, cursor, srcs);
  wpad_kernel<<<(6 * 320 * DP + 255) / 256, 256, 0, stream>>>(convW, postW, Wp);
  embed_kernel<<<NN, 128, 0, stream>>>(xa, emb, P);

  for (int l = 0; l < NLAY; ++l) {
    gemm_kernel<<<(NN / BM) * 5, 256, 0, stream>>>(
        P, Wp + (size_t)l * 320 * DP, Q,
        l ? bnscale : nullptr, l ? bnshift : nullptr, dinv, nullptr);
    hipMemsetAsync(bn_sum, 0, 2 * DP * sizeof(float), stream);
    spmm_kernel<<<NN / 64, 256, 0, stream>>>(Q, P, indptr, srcs, dinv,
                                             convB + (size_t)l * DIM, bn_sum, bn_sq);
    bn_finalize_kernel<<<1, DP, 0, stream>>>(bn_sum, bn_sq, gamma + (size_t)l * DIM,
                                             beta + (size_t)l * DIM, bnscale, bnshift);
  }

  gemm_kernel<<<(NN / BM) * 5, 256, 0, stream>>>(
      P, Wp + (size_t)5 * 320 * DP, Q, bnscale, bnshift, nullptr, postB);

  decode_kernel<<<NGRAPH / 4, 256, 0, stream>>>(Q, out);
}

// Round 5
// 1265.467 us; speedup vs baseline: 2.3930x; 1.0312x over previous
//
#include <hip/hip_runtime.h>
#include <hip/hip_bf16.h>
#include <cstdint>

#define NN 131072      // nodes
#define NE 524288      // directed edges
#define DIM 275        // feature dim
#define DP 288         // padded stride (multiple of 16)
#define NFEAT 9
#define NVOC 128
#define NLAY 5
#define NPG 64
#define NGRAPH 2048
#define BN_EPS 1e-5f
#define BM 128
#define BK 32
#define NEPAD (NE + 3 * NN)   // max padded edge count

typedef unsigned short u16;
typedef __attribute__((ext_vector_type(8))) short s16x8;
typedef __attribute__((ext_vector_type(4))) float f32x4;

__device__ __forceinline__ float bf2f(u16 u) {
  union { unsigned int i; float f; } x; x.i = ((unsigned int)u) << 16; return x.f;
}
__device__ __forceinline__ u16 f2bf(float f) {
  union { float f; unsigned int i; } x; x.f = f;
  unsigned int r = x.i + 0x7fffu + ((x.i >> 16) & 1u);
  return (u16)(r >> 16);
}

// ---------------- graph preprocessing ----------------

__global__ void hist_kernel(const int* __restrict__ ei, int* __restrict__ cnt) {
  int e = blockIdx.x * 256 + threadIdx.x;
  if (e < NE) atomicAdd(&cnt[ei[NE + e]], 1);
}

__global__ void pad_dinv_kernel(const int* __restrict__ cnt, int* __restrict__ cnt_pad,
                                float* __restrict__ dinv) {
  int v = blockIdx.x * 256 + threadIdx.x;
  if (v < NN) {
    int c = cnt[v];
    cnt_pad[v] = (c + 3) & ~3;
    dinv[v] = rsqrtf(1.0f + (float)c);
  }
}

__global__ void scan_block_kernel(const int* __restrict__ in, int* __restrict__ out_ex,
                                  int* __restrict__ partials) {
  __shared__ int buf[2][1024];
  int t = threadIdx.x;
  int idx = blockIdx.x * 1024 + t;
  int v = in[idx];
  buf[0][t] = v;
  __syncthreads();
  int cur = 0;
  for (int off = 1; off < 1024; off <<= 1) {
    int x = buf[cur][t];
    if (t >= off) x += buf[cur][t - off];
    buf[cur ^ 1][t] = x;
    __syncthreads();
    cur ^= 1;
  }
  out_ex[idx] = buf[cur][t] - v;
  if (t == 1023) partials[blockIdx.x] = buf[cur][t];
}

__global__ void scan_partials_kernel(int* partials) {
  __shared__ int buf[2][128];
  int t = threadIdx.x;
  int v = partials[t];
  buf[0][t] = v;
  __syncthreads();
  int cur = 0;
  for (int off = 1; off < 128; off <<= 1) {
    int x = buf[cur][t];
    if (t >= off) x += buf[cur][t - off];
    buf[cur ^ 1][t] = x;
    __syncthreads();
    cur ^= 1;
  }
  partials[t] = buf[cur][t] - v;
}

__global__ void add_offsets_kernel(int* __restrict__ indptr, const int* __restrict__ partials,
                                   int* __restrict__ cursor, const int* __restrict__ cnt_pad) {
  int i = blockIdx.x * 256 + threadIdx.x;
  if (i < NN) {
    int v = indptr[i] + partials[i >> 10];
    indptr[i] = v;
    cursor[i] = v;
    if (i == NN - 1) indptr[NN] = v + cnt_pad[NN - 1];
  }
}

__global__ void fill_csr_kernel(const int* __restrict__ ei, int* __restrict__ cursor,
                                int* __restrict__ srcs) {
  int e = blockIdx.x * 256 + threadIdx.x;
  if (e < NE) {
    int c = ei[NE + e];
    int p = atomicAdd(&cursor[c], 1);
    srcs[p] = ei[e];
  }
}

// pad slots point at the all-zeros row NN
__global__ void pad_fill_kernel(const int* __restrict__ cursor, const int* __restrict__ indptr,
                                int* __restrict__ srcs) {
  int v = blockIdx.x * 256 + threadIdx.x;
  if (v < NN) {
    int pe = indptr[v + 1];
    for (int p = cursor[v]; p < pe; ++p) srcs[p] = NN;
  }
}

__global__ void zrow_kernel(u16* __restrict__ P, u16* __restrict__ Q) {
  int i = threadIdx.x;
  if (i < DP) {
    P[(size_t)NN * DP + i] = 0;
    Q[(size_t)NN * DP + i] = 0;
  }
}

__global__ void wpad_kernel(const float* __restrict__ convW, const float* __restrict__ postW,
                            u16* __restrict__ Wp) {
  int i = blockIdx.x * 256 + threadIdx.x;
  const int total = 6 * 320 * DP;
  if (i >= total) return;
  int k = i % DP;
  int r = i / DP;
  int j = r % 320;
  int m = r / 320;
  float val = 0.f;
  if (j < DIM && k < DIM)
    val = (m < 5) ? convW[((size_t)m * DIM + j) * DIM + k] : postW[(size_t)j * DIM + k];
  Wp[i] = f2bf(val);
}

// ---------------- atom encoder ----------------

__global__ void embed_kernel(const int* __restrict__ xa, const float* __restrict__ emb,
                             u16* __restrict__ P) {
  int n = blockIdx.x;
  int idx[NFEAT];
#pragma unroll
  for (int f = 0; f < NFEAT; ++f) idx[f] = xa[n * NFEAT + f];
  for (int d = threadIdx.x; d < DP; d += 128) {
    float s = 0.f;
    if (d < DIM) {
#pragma unroll
      for (int f = 0; f < NFEAT; ++f) s += emb[((size_t)f * NVOC + idx[f]) * DIM + d];
    }
    P[(size_t)n * DP + d] = f2bf(s);
  }
}

// ---------------- MFMA GEMM (BM=128, col tile 160, 2 col passes) ----------------
// C = rowscale .* (act(A) @ W^T) + colbias, act = relu(x*scale+shift) if scale.
// Grid 2048: b = grp*16 + col*8 + pan8; panel = grp*8+pan8 -> both col passes of
// a panel share b%8 (same XCD) and are dispatch-adjacent. col0 = col*128, the
// 160-wide tiles overlap in cols 128..159: both blocks write bit-identical bf16.

__device__ __forceinline__ uint4 xform8(uint4 r, const float* __restrict__ sc,
                                        const float* __restrict__ sh, int k) {
  union { uint4 u; u16 h[8]; } in, out;
  in.u = r;
#pragma unroll
  for (int j = 0; j < 8; ++j) {
    float x = fmaf(bf2f(in.h[j]), sc[k + j], sh[k + j]);
    out.h[j] = f2bf(fmaxf(x, 0.f));
  }
  return out.u;
}

__launch_bounds__(256)
__global__ void gemm_kernel(const u16* __restrict__ A, const u16* __restrict__ Wp,
                            u16* __restrict__ C,
                            const float* __restrict__ scale, const float* __restrict__ shift,
                            const float* __restrict__ rowscale, const float* __restrict__ colbias) {
  __shared__ __align__(16) u16 Asl[BM * BK];     // 8 KB
  __shared__ __align__(16) u16 Bsl[160 * BK];    // 10 KB
  const int tid = threadIdx.x;
  const int lane = tid & 63;
  const int wv = tid >> 6, wm = wv & 1, wn = wv >> 1;   // waves 2(M) x 2(N)
  const int b = blockIdx.x;
  const int grp = b >> 4, rem = b & 15;
  const int col = rem >> 3, pan8 = rem & 7;
  const int row0 = (grp * 8 + pan8) * BM, col0 = col * 128;

  const int sr = tid >> 2, ssl = tid & 3;
  const int swz = ((ssl ^ (sr & 3) ^ ((sr >> 2) & 3)) << 3);   // row-invariant mod 64
  const int aw0 = sr * BK + swz;
  const u16* ag0 = A + (size_t)(row0 + sr) * DP + ssl * 8;
  const u16* ag1 = ag0 + (size_t)64 * DP;
  const u16* bg0 = Wp + (size_t)(col0 + sr) * DP + ssl * 8;
  const u16* bg1 = bg0 + (size_t)64 * DP;
  const u16* bg2 = bg0 + (size_t)128 * DP;   // tid<128 only (rows 128..159)
  const bool st2 = (tid < 128);

  const int fr = lane & 15, fs = lane >> 4;
  const int fswz = ((fs ^ (fr & 3) ^ ((fr >> 2) & 3)) << 3);
  int aoff[4], boff[5];
#pragma unroll
  for (int i = 0; i < 4; ++i) aoff[i] = (wm * 64 + i * 16 + fr) * BK + fswz;
#pragma unroll
  for (int j = 0; j < 5; ++j) boff[j] = (wn * 80 + j * 16 + fr) * BK + fswz;

  const bool bn = (scale != nullptr);
  const int NS = DP / BK;   // 9

  // prologue: stage k-step 0
  {
    uint4 ra0 = *(const uint4*)(ag0);
    uint4 ra1 = *(const uint4*)(ag1);
    uint4 rb0 = *(const uint4*)(bg0);
    uint4 rb1 = *(const uint4*)(bg1);
    uint4 rb2;
    if (st2) rb2 = *(const uint4*)(bg2);
    if (bn) {
      ra0 = xform8(ra0, scale, shift, ssl * 8);
      ra1 = xform8(ra1, scale, shift, ssl * 8);
    }
    *(uint4*)&Asl[aw0] = ra0;
    *(uint4*)&Asl[aw0 + 64 * BK] = ra1;
    *(uint4*)&Bsl[aw0] = rb0;
    *(uint4*)&Bsl[aw0 + 64 * BK] = rb1;
    if (st2) *(uint4*)&Bsl[aw0 + 128 * BK] = rb2;
  }
  __syncthreads();

  f32x4 acc[4][5];
#pragma unroll
  for (int i = 0; i < 4; ++i)
#pragma unroll
    for (int j = 0; j < 5; ++j) acc[i][j] = (f32x4){0.f, 0.f, 0.f, 0.f};

  for (int s = 0; s < NS; ++s) {
    const bool more = (s < NS - 1);
    uint4 na0, na1, nb0, nb1, nb2;
    if (more) {   // issue next-tile global loads; land during MFMA block
      na0 = *(const uint4*)(ag0 + (s + 1) * BK);
      na1 = *(const uint4*)(ag1 + (s + 1) * BK);
      nb0 = *(const uint4*)(bg0 + (s + 1) * BK);
      nb1 = *(const uint4*)(bg1 + (s + 1) * BK);
      if (st2) nb2 = *(const uint4*)(bg2 + (s + 1) * BK);
    }
    s16x8 af[4], bf[5];
#pragma unroll
    for (int i = 0; i < 4; ++i) af[i] = *(const s16x8*)&Asl[aoff[i]];
#pragma unroll
    for (int j = 0; j < 5; ++j) bf[j] = *(const s16x8*)&Bsl[boff[j]];
#pragma unroll
    for (int i = 0; i < 4; ++i)
#pragma unroll
      for (int j = 0; j < 5; ++j)
        acc[i][j] = __builtin_amdgcn_mfma_f32_16x16x32_bf16(af[i], bf[j], acc[i][j], 0, 0, 0);
    if (more) {
      __syncthreads();   // all waves done reading LDS for step s
      int k2 = (s + 1) * BK + ssl * 8;
      if (bn) {
        na0 = xform8(na0, scale, shift, k2);
        na1 = xform8(na1, scale, shift, k2);
      }
      *(uint4*)&Asl[aw0] = na0;
      *(uint4*)&Asl[aw0 + 64 * BK] = na1;
      *(uint4*)&Bsl[aw0] = nb0;
      *(uint4*)&Bsl[aw0 + 64 * BK] = nb1;
      if (st2) *(uint4*)&Bsl[aw0 + 128 * BK] = nb2;
      __syncthreads();
    }
  }

#pragma unroll
  for (int i = 0; i < 4; ++i) {
    int gr0 = row0 + wm * 64 + i * 16 + fs * 4;
    float rs[4];
#pragma unroll
    for (int r = 0; r < 4; ++r) rs[r] = rowscale ? rowscale[gr0 + r] : 1.f;
#pragma unroll
    for (int j = 0; j < 5; ++j) {
      int gc = col0 + wn * 80 + j * 16 + fr;
      if (gc < DP) {
        float cb = (colbias && gc < DIM) ? colbias[gc] : 0.f;
#pragma unroll
        for (int r = 0; r < 4; ++r) {
          u16 o = (gc < DIM) ? f2bf(fmaf(acc[i][j][r], rs[r], cb)) : (u16)0;
          C[(size_t)(gr0 + r) * DP + gc] = o;
        }
      }
    }
  }
}

// ---------------- SpMM aggregate + fused BN-stat partials ----------------
// Padded CSR: every node's edge count is a multiple of 4; pad edges point at
// the zero row NN. Inner loop is branch-free 4-batches: int4 index load + 4
// independent row gathers in flight.

__launch_bounds__(256)
__global__ void spmm_kernel(const u16* __restrict__ X, u16* __restrict__ Y,
                            const int* __restrict__ indptr, const int* __restrict__ srcs,
                            const float* __restrict__ dinv, const float* __restrict__ bias,
                            float* __restrict__ bn_sum, float* __restrict__ bn_sq) {
  __shared__ float ls[DP], lq[DP];
  int tid = threadIdx.x;
  for (int i = tid; i < DP; i += 256) { ls[i] = 0.f; lq[i] = 0.f; }
  __syncthreads();
  int lane = tid & 63, wv = tid >> 6;
  int vbase = blockIdx.x * 64 + wv * 16;
  int c0 = lane << 2;
  int c1 = 256 + (lane << 2);
  bool tl = lane < 8;
  float bia[4], bib[4];
#pragma unroll
  for (int j = 0; j < 4; ++j) bia[j] = bias[c0 + j];
#pragma unroll
  for (int j = 0; j < 4; ++j) bib[j] = (tl && c1 + j < DIM) ? bias[c1 + j] : 0.f;
  float s0[4] = {}, q0[4] = {}, s1[4] = {}, q1[4] = {};
  for (int v = vbase; v < vbase + 16; ++v) {
    const u16* xv = X + (size_t)v * DP;
    uint2 m = *(const uint2*)(xv + c0);
    float a[4] = {bf2f((u16)m.x), bf2f((u16)(m.x >> 16)), bf2f((u16)m.y), bf2f((u16)(m.y >> 16))};
    float b[4] = {0.f, 0.f, 0.f, 0.f};
    if (tl) {
      uint2 t = *(const uint2*)(xv + c1);
      b[0] = bf2f((u16)t.x); b[1] = bf2f((u16)(t.x >> 16));
      b[2] = bf2f((u16)t.y); b[3] = bf2f((u16)(t.y >> 16));
    }
    int e0 = indptr[v], e1 = indptr[v + 1];
    for (int e = e0; e < e1; e += 4) {
      int4 ii = *(const int4*)(srcs + e);
      const u16* x0 = X + (size_t)ii.x * DP;
      const u16* x1 = X + (size_t)ii.y * DP;
      const u16* x2 = X + (size_t)ii.z * DP;
      const u16* x3 = X + (size_t)ii.w * DP;
      uint2 m0 = *(const uint2*)(x0 + c0);
      uint2 m1 = *(const uint2*)(x1 + c0);
      uint2 m2 = *(const uint2*)(x2 + c0);
      uint2 m3 = *(const uint2*)(x3 + c0);
      uint2 t0, t1, t2, t3;
      if (tl) {
        t0 = *(const uint2*)(x0 + c1);
        t1 = *(const uint2*)(x1 + c1);
        t2 = *(const uint2*)(x2 + c1);
        t3 = *(const uint2*)(x3 + c1);
      }
      a[0] += bf2f((u16)m0.x) + bf2f((u16)m1.x) + bf2f((u16)m2.x) + bf2f((u16)m3.x);
      a[1] += bf2f((u16)(m0.x >> 16)) + bf2f((u16)(m1.x >> 16)) + bf2f((u16)(m2.x >> 16)) + bf2f((u16)(m3.x >> 16));
      a[2] += bf2f((u16)m0.y) + bf2f((u16)m1.y) + bf2f((u16)m2.y) + bf2f((u16)m3.y);
      a[3] += bf2f((u16)(m0.y >> 16)) + bf2f((u16)(m1.y >> 16)) + bf2f((u16)(m2.y >> 16)) + bf2f((u16)(m3.y >> 16));
      if (tl) {
        b[0] += bf2f((u16)t0.x) + bf2f((u16)t1.x) + bf2f((u16)t2.x) + bf2f((u16)t3.x);
        b[1] += bf2f((u16)(t0.x >> 16)) + bf2f((u16)(t1.x >> 16)) + bf2f((u16)(t2.x >> 16)) + bf2f((u16)(t3.x >> 16));
        b[2] += bf2f((u16)t0.y) + bf2f((u16)t1.y) + bf2f((u16)t2.y) + bf2f((u16)t3.y);
        b[3] += bf2f((u16)(t0.y >> 16)) + bf2f((u16)(t1.y >> 16)) + bf2f((u16)(t2.y >> 16)) + bf2f((u16)(t3.y >> 16));
      }
    }
    float dv = dinv[v];
    u16* yv = Y + (size_t)v * DP;
    float y[4];
#pragma unroll
    for (int j = 0; j < 4; ++j) {
      y[j] = fmaf(dv, a[j], bia[j]);
      s0[j] += y[j]; q0[j] += y[j] * y[j];
    }
    uint2 w;
    w.x = (unsigned)f2bf(y[0]) | ((unsigned)f2bf(y[1]) << 16);
    w.y = (unsigned)f2bf(y[2]) | ((unsigned)f2bf(y[3]) << 16);
    *(uint2*)(yv + c0) = w;
    if (tl) {
      float z[4];
#pragma unroll
      for (int j = 0; j < 4; ++j) {
        z[j] = fmaf(dv, b[j], bib[j]);
        s1[j] += z[j]; q1[j] += z[j] * z[j];
      }
      uint2 w2;
      w2.x = (unsigned)f2bf(z[0]) | ((unsigned)f2bf(z[1]) << 16);
      w2.y = (unsigned)f2bf(z[2]) | ((unsigned)f2bf(z[3]) << 16);
      *(uint2*)(yv + c1) = w2;
    }
  }
#pragma unroll
  for (int j = 0; j < 4; ++j) { atomicAdd(&ls[c0 + j], s0[j]); atomicAdd(&lq[c0 + j], q0[j]); }
  if (tl) {
#pragma unroll
    for (int j = 0; j < 4; ++j) { atomicAdd(&ls[c1 + j], s1[j]); atomicAdd(&lq[c1 + j], q1[j]); }
  }
  __syncthreads();
  for (int i = tid; i < DP; i += 256) {
    atomicAdd(&bn_sum[i], ls[i]);
    atomicAdd(&bn_sq[i], lq[i]);
  }
}

__global__ void bn_finalize_kernel(const float* __restrict__ bn_sum, const float* __restrict__ bn_sq,
                                   const float* __restrict__ gamma, const float* __restrict__ beta,
                                   float* __restrict__ scale, float* __restrict__ shift) {
  int d = threadIdx.x;
  if (d >= DP) return;
  if (d < DIM) {
    const float invN = 1.0f / (float)NN;
    float mu = bn_sum[d] * invN;
    float var = bn_sq[d] * invN - mu * mu;
    float rstd = rsqrtf(var + BN_EPS);
    float sc = gamma[d] * rstd;
    scale[d] = sc;
    shift[d] = fmaf(-mu, sc, beta[d]);
  } else {
    scale[d] = 0.f;
    shift[d] = 0.f;
  }
}

// ---------------- MFMA Gram decode ----------------

__launch_bounds__(256)
__global__ void decode_kernel(const u16* __restrict__ H, float* __restrict__ out) {
  __shared__ __align__(16) u16 tile[4][2][NPG * BK];
  int tid = threadIdx.x, lane = tid & 63, wv = tid >> 6;
  int g = blockIdx.x * 4 + wv;
  const u16* Hg = H + (size_t)g * NPG * DP;
  const int ssl = lane & 3;
  int soff[4];
  const u16* sg[4];
#pragma unroll
  for (int i = 0; i < 4; ++i) {
    int r = (lane >> 2) + i * 16;
    soff[i] = r * BK + ((ssl ^ (r & 3) ^ ((r >> 2) & 3)) << 3);
    sg[i] = Hg + (size_t)r * DP + ssl * 8;
  }
  const int fr = lane & 15, fs = lane >> 4;
  const int fswz = ((fs ^ (fr & 3) ^ ((fr >> 2) & 3)) << 3);
  int foff[4];
#pragma unroll
  for (int i = 0; i < 4; ++i) foff[i] = (i * 16 + fr) * BK + fswz;

  u16* t0 = tile[wv][0];
  u16* t1 = tile[wv][1];
  uint4 rg[4];
#pragma unroll
  for (int i = 0; i < 4; ++i) rg[i] = *(const uint4*)(sg[i]);
#pragma unroll
  for (int i = 0; i < 4; ++i) *(uint4*)&t0[soff[i]] = rg[i];

  f32x4 acc[4][4];
#pragma unroll
  for (int i = 0; i < 4; ++i)
#pragma unroll
    for (int j = 0; j < 4; ++j) acc[i][j] = (f32x4){0.f, 0.f, 0.f, 0.f};

  for (int s = 0; s < DP / BK; ++s) {
    u16* cur = (s & 1) ? t1 : t0;
    u16* nxt = (s & 1) ? t0 : t1;
    const bool more = (s < DP / BK - 1);
    if (more) {
#pragma unroll
      for (int i = 0; i < 4; ++i) rg[i] = *(const uint4*)(sg[i] + (s + 1) * BK);
    }
    s16x8 af[4];
#pragma unroll
    for (int i = 0; i < 4; ++i) af[i] = *(const s16x8*)&cur[foff[i]];
#pragma unroll
    for (int i = 0; i < 4; ++i)
#pragma unroll
      for (int j = 0; j < 4; ++j)
        acc[i][j] = __builtin_amdgcn_mfma_f32_16x16x32_bf16(af[i], af[j], acc[i][j], 0, 0, 0);
    if (more) {
#pragma unroll
      for (int i = 0; i < 4; ++i) *(uint4*)&nxt[soff[i]] = rg[i];
    }
  }
  float* og = out + (size_t)g * NPG * NPG;
#pragma unroll
  for (int i = 0; i < 4; ++i) {
    int m0 = i * 16 + fs * 4;
#pragma unroll
    for (int j = 0; j < 4; ++j) {
      int n = j * 16 + fr;
#pragma unroll
      for (int r = 0; r < 4; ++r) og[(m0 + r) * NPG + n] = acc[i][j][r];
    }
  }
}

// ---------------- launch ----------------

extern "C" void kernel_launch(void* const* d_in, const int* in_sizes, int n_in,
                              void* d_out, int out_size, void* d_ws, size_t ws_size,
                              hipStream_t stream) {
  const int* xa = (const int*)d_in[0];
  const int* ei = (const int*)d_in[1];
  const float* emb = (const float*)d_in[2];
  const float* convW = (const float*)d_in[3];
  const float* convB = (const float*)d_in[4];
  const float* gamma = (const float*)d_in[5];
  const float* beta = (const float*)d_in[6];
  const float* postW = (const float*)d_in[7];
  const float* postB = (const float*)d_in[8];
  float* out = (float*)d_out;

  char* w = (char*)d_ws;
  u16* P = (u16*)w;          w += (size_t)(NN + 1) * DP * sizeof(u16);
  u16* Q = (u16*)w;          w += (size_t)(NN + 1) * DP * sizeof(u16);
  u16* Wp = (u16*)w;         w += (size_t)6 * 320 * DP * sizeof(u16);
  float* dinv = (float*)w;   w += (size_t)NN * sizeof(float);
  int* cnt = (int*)w;        w += (size_t)NN * sizeof(int);
  int* cnt_pad = (int*)w;    w += (size_t)NN * sizeof(int);
  int* indptr = (int*)w;     w += (size_t)(NN + 64) * sizeof(int);
  int* cursor = (int*)w;     w += (size_t)NN * sizeof(int);
  int* srcs = (int*)w;       w += (size_t)NEPAD * sizeof(int);
  int* partials = (int*)w;   w += 256 * sizeof(int);
  float* bn_sum = (float*)w; w += DP * sizeof(float);
  float* bn_sq = (float*)w;  w += DP * sizeof(float);
  float* bnscale = (float*)w; w += DP * sizeof(float);
  float* bnshift = (float*)w; w += DP * sizeof(float);

  size_t need = (size_t)(w - (char*)d_ws);
  if (ws_size < need) return;

  hipMemsetAsync(cnt, 0, (size_t)NN * sizeof(int), stream);
  hist_kernel<<<NE / 256, 256, 0, stream>>>(ei, cnt);
  pad_dinv_kernel<<<NN / 256, 256, 0, stream>>>(cnt, cnt_pad, dinv);
  scan_block_kernel<<<NN / 1024, 1024, 0, stream>>>(cnt_pad, indptr, partials);
  scan_partials_kernel<<<1, 128, 0, stream>>>(partials);
  add_offsets_kernel<<<NN / 256, 256, 0, stream>>>(indptr, partials, cursor, cnt_pad);
  fill_csr_kernel<<<NE / 256, 256, 0, stream>>>(ei, cursor, srcs);
  pad_fill_kernel<<<NN / 256, 256, 0, stream>>>(cursor, indptr, srcs);
  wpad_kernel<<<(6 * 320 * DP + 255) / 256, 256, 0, stream>>>(convW, postW, Wp);
  embed_kernel<<<NN, 128, 0, stream>>>(xa, emb, P);
  zrow_kernel<<<1, 288, 0, stream>>>(P, Q);

  for (int l = 0; l < NLAY; ++l) {
    gemm_kernel<<<(NN / BM) * 2, 256, 0, stream>>>(
        P, Wp + (size_t)l * 320 * DP, Q,
        l ? bnscale : nullptr, l ? bnshift : nullptr, dinv, nullptr);
    hipMemsetAsync(bn_sum, 0, 2 * DP * sizeof(float), stream);
    spmm_kernel<<<NN / 64, 256, 0, stream>>>(Q, P, indptr, srcs, dinv,
                                             convB + (size_t)l * DIM, bn_sum, bn_sq);
    bn_finalize_kernel<<<1, DP, 0, stream>>>(bn_sum, bn_sq, gamma + (size_t)l * DIM,
                                             beta + (size_t)l * DIM, bnscale, bnshift);
  }

  gemm_kernel<<<(NN / BM) * 2, 256, 0, stream>>>(
      P, Wp + (size_t)5 * 320 * DP, Q, bnscale, bnshift, nullptr, postB);

  decode_kernel<<<NGRAPH / 4, 256, 0, stream>>>(Q, out);
}

// Round 6
// 1093.102 us; speedup vs baseline: 2.7703x; 1.1577x over previous
//
#include <hip/hip_runtime.h>
#include <hip/hip_bf16.h>
#include <cstdint>

#define NN 131072      // nodes
#define NE 524288      // directed edges
#define DIM 275        // feature dim
#define DP 288         // padded stride (multiple of 16)
#define NFEAT 9
#define NVOC 128
#define NLAY 5
#define NPG 64
#define NGRAPH 2048
#define BN_EPS 1e-5f
#define BM 128
#define BK 32
#define NEPAD (NE + 3 * NN)   // max padded edge count
#define LDSE 1536             // per-block staged edge indices

typedef unsigned short u16;
typedef __attribute__((ext_vector_type(8))) short s16x8;
typedef __attribute__((ext_vector_type(4))) float f32x4;

__device__ __forceinline__ float bf2f(u16 u) {
  union { unsigned int i; float f; } x; x.i = ((unsigned int)u) << 16; return x.f;
}
__device__ __forceinline__ u16 f2bf(float f) {
  union { float f; unsigned int i; } x; x.f = f;
  unsigned int r = x.i + 0x7fffu + ((x.i >> 16) & 1u);
  return (u16)(r >> 16);
}
__device__ __forceinline__ void acc4(float* a, uint2 m) {
  a[0] += bf2f((u16)m.x); a[1] += bf2f((u16)(m.x >> 16));
  a[2] += bf2f((u16)m.y); a[3] += bf2f((u16)(m.y >> 16));
}

// ---------------- graph preprocessing ----------------

__global__ void hist_kernel(const int* __restrict__ ei, int* __restrict__ cnt) {
  int e = blockIdx.x * 256 + threadIdx.x;
  if (e < NE) atomicAdd(&cnt[ei[NE + e]], 1);
}

__global__ void pad_dinv_kernel(const int* __restrict__ cnt, int* __restrict__ cnt_pad,
                                float* __restrict__ dinv) {
  int v = blockIdx.x * 256 + threadIdx.x;
  if (v < NN) {
    int c = cnt[v];
    cnt_pad[v] = (c + 3) & ~3;
    dinv[v] = rsqrtf(1.0f + (float)c);
  }
}

__global__ void scan_block_kernel(const int* __restrict__ in, int* __restrict__ out_ex,
                                  int* __restrict__ partials) {
  __shared__ int buf[2][1024];
  int t = threadIdx.x;
  int idx = blockIdx.x * 1024 + t;
  int v = in[idx];
  buf[0][t] = v;
  __syncthreads();
  int cur = 0;
  for (int off = 1; off < 1024; off <<= 1) {
    int x = buf[cur][t];
    if (t >= off) x += buf[cur][t - off];
    buf[cur ^ 1][t] = x;
    __syncthreads();
    cur ^= 1;
  }
  out_ex[idx] = buf[cur][t] - v;
  if (t == 1023) partials[blockIdx.x] = buf[cur][t];
}

__global__ void scan_partials_kernel(int* partials) {
  __shared__ int buf[2][128];
  int t = threadIdx.x;
  int v = partials[t];
  buf[0][t] = v;
  __syncthreads();
  int cur = 0;
  for (int off = 1; off < 128; off <<= 1) {
    int x = buf[cur][t];
    if (t >= off) x += buf[cur][t - off];
    buf[cur ^ 1][t] = x;
    __syncthreads();
    cur ^= 1;
  }
  partials[t] = buf[cur][t] - v;
}

__global__ void add_offsets_kernel(int* __restrict__ indptr, const int* __restrict__ partials,
                                   int* __restrict__ cursor, const int* __restrict__ cnt_pad) {
  int i = blockIdx.x * 256 + threadIdx.x;
  if (i < NN) {
    int v = indptr[i] + partials[i >> 10];
    indptr[i] = v;
    cursor[i] = v;
    if (i == NN - 1) indptr[NN] = v + cnt_pad[NN - 1];
  }
}

__global__ void fill_csr_kernel(const int* __restrict__ ei, int* __restrict__ cursor,
                                int* __restrict__ srcs) {
  int e = blockIdx.x * 256 + threadIdx.x;
  if (e < NE) {
    int c = ei[NE + e];
    int p = atomicAdd(&cursor[c], 1);
    srcs[p] = ei[e];
  }
}

// pad slots point at the all-zeros row NN
__global__ void pad_fill_kernel(const int* __restrict__ cursor, const int* __restrict__ indptr,
                                int* __restrict__ srcs) {
  int v = blockIdx.x * 256 + threadIdx.x;
  if (v < NN) {
    int pe = indptr[v + 1];
    for (int p = cursor[v]; p < pe; ++p) srcs[p] = NN;
  }
}

__global__ void zrow_kernel(u16* __restrict__ P, u16* __restrict__ Q) {
  int i = threadIdx.x;
  if (i < DP) {
    P[(size_t)NN * DP + i] = 0;
    Q[(size_t)NN * DP + i] = 0;
  }
}

__global__ void wpad_kernel(const float* __restrict__ convW, const float* __restrict__ postW,
                            u16* __restrict__ Wp) {
  int i = blockIdx.x * 256 + threadIdx.x;
  const int total = 6 * 320 * DP;
  if (i >= total) return;
  int k = i % DP;
  int r = i / DP;
  int j = r % 320;
  int m = r / 320;
  float val = 0.f;
  if (j < DIM && k < DIM)
    val = (m < 5) ? convW[((size_t)m * DIM + j) * DIM + k] : postW[(size_t)j * DIM + k];
  Wp[i] = f2bf(val);
}

// ---------------- atom encoder ----------------

__global__ void embed_kernel(const int* __restrict__ xa, const float* __restrict__ emb,
                             u16* __restrict__ P) {
  int n = blockIdx.x;
  int idx[NFEAT];
#pragma unroll
  for (int f = 0; f < NFEAT; ++f) idx[f] = xa[n * NFEAT + f];
  for (int d = threadIdx.x; d < DP; d += 128) {
    float s = 0.f;
    if (d < DIM) {
#pragma unroll
      for (int f = 0; f < NFEAT; ++f) s += emb[((size_t)f * NVOC + idx[f]) * DIM + d];
    }
    P[(size_t)n * DP + d] = f2bf(s);
  }
}

// ---------------- MFMA GEMM (BM=128, col tile 160, 2 col passes) ----------------
// C = rowscale .* (act(A) @ W^T) + colbias, act = relu(x*scale+shift) if scale.

__device__ __forceinline__ uint4 xform8(uint4 r, const float* __restrict__ sc,
                                        const float* __restrict__ sh, int k) {
  union { uint4 u; u16 h[8]; } in, out;
  in.u = r;
#pragma unroll
  for (int j = 0; j < 8; ++j) {
    float x = fmaf(bf2f(in.h[j]), sc[k + j], sh[k + j]);
    out.h[j] = f2bf(fmaxf(x, 0.f));
  }
  return out.u;
}

__launch_bounds__(256)
__global__ void gemm_kernel(const u16* __restrict__ A, const u16* __restrict__ Wp,
                            u16* __restrict__ C,
                            const float* __restrict__ scale, const float* __restrict__ shift,
                            const float* __restrict__ rowscale, const float* __restrict__ colbias) {
  __shared__ __align__(16) u16 Asl[BM * BK];     // 8 KB
  __shared__ __align__(16) u16 Bsl[160 * BK];    // 10 KB
  const int tid = threadIdx.x;
  const int lane = tid & 63;
  const int wv = tid >> 6, wm = wv & 1, wn = wv >> 1;   // waves 2(M) x 2(N)
  const int b = blockIdx.x;
  const int grp = b >> 4, rem = b & 15;
  const int col = rem >> 3, pan8 = rem & 7;
  const int row0 = (grp * 8 + pan8) * BM, col0 = col * 128;

  const int sr = tid >> 2, ssl = tid & 3;
  const int swz = ((ssl ^ (sr & 3) ^ ((sr >> 2) & 3)) << 3);   // row-invariant mod 64
  const int aw0 = sr * BK + swz;
  const u16* ag0 = A + (size_t)(row0 + sr) * DP + ssl * 8;
  const u16* ag1 = ag0 + (size_t)64 * DP;
  const u16* bg0 = Wp + (size_t)(col0 + sr) * DP + ssl * 8;
  const u16* bg1 = bg0 + (size_t)64 * DP;
  const u16* bg2 = bg0 + (size_t)128 * DP;   // tid<128 only (rows 128..159)
  const bool st2 = (tid < 128);

  const int fr = lane & 15, fs = lane >> 4;
  const int fswz = ((fs ^ (fr & 3) ^ ((fr >> 2) & 3)) << 3);
  int aoff[4], boff[5];
#pragma unroll
  for (int i = 0; i < 4; ++i) aoff[i] = (wm * 64 + i * 16 + fr) * BK + fswz;
#pragma unroll
  for (int j = 0; j < 5; ++j) boff[j] = (wn * 80 + j * 16 + fr) * BK + fswz;

  const bool bn = (scale != nullptr);
  const int NS = DP / BK;   // 9

  {
    uint4 ra0 = *(const uint4*)(ag0);
    uint4 ra1 = *(const uint4*)(ag1);
    uint4 rb0 = *(const uint4*)(bg0);
    uint4 rb1 = *(const uint4*)(bg1);
    uint4 rb2;
    if (st2) rb2 = *(const uint4*)(bg2);
    if (bn) {
      ra0 = xform8(ra0, scale, shift, ssl * 8);
      ra1 = xform8(ra1, scale, shift, ssl * 8);
    }
    *(uint4*)&Asl[aw0] = ra0;
    *(uint4*)&Asl[aw0 + 64 * BK] = ra1;
    *(uint4*)&Bsl[aw0] = rb0;
    *(uint4*)&Bsl[aw0 + 64 * BK] = rb1;
    if (st2) *(uint4*)&Bsl[aw0 + 128 * BK] = rb2;
  }
  __syncthreads();

  f32x4 acc[4][5];
#pragma unroll
  for (int i = 0; i < 4; ++i)
#pragma unroll
    for (int j = 0; j < 5; ++j) acc[i][j] = (f32x4){0.f, 0.f, 0.f, 0.f};

  for (int s = 0; s < NS; ++s) {
    const bool more = (s < NS - 1);
    uint4 na0, na1, nb0, nb1, nb2;
    if (more) {
      na0 = *(const uint4*)(ag0 + (s + 1) * BK);
      na1 = *(const uint4*)(ag1 + (s + 1) * BK);
      nb0 = *(const uint4*)(bg0 + (s + 1) * BK);
      nb1 = *(const uint4*)(bg1 + (s + 1) * BK);
      if (st2) nb2 = *(const uint4*)(bg2 + (s + 1) * BK);
    }
    s16x8 af[4], bf[5];
#pragma unroll
    for (int i = 0; i < 4; ++i) af[i] = *(const s16x8*)&Asl[aoff[i]];
#pragma unroll
    for (int j = 0; j < 5; ++j) bf[j] = *(const s16x8*)&Bsl[boff[j]];
#pragma unroll
    for (int i = 0; i < 4; ++i)
#pragma unroll
      for (int j = 0; j < 5; ++j)
        acc[i][j] = __builtin_amdgcn_mfma_f32_16x16x32_bf16(af[i], bf[j], acc[i][j], 0, 0, 0);
    if (more) {
      __syncthreads();
      int k2 = (s + 1) * BK + ssl * 8;
      if (bn) {
        na0 = xform8(na0, scale, shift, k2);
        na1 = xform8(na1, scale, shift, k2);
      }
      *(uint4*)&Asl[aw0] = na0;
      *(uint4*)&Asl[aw0 + 64 * BK] = na1;
      *(uint4*)&Bsl[aw0] = nb0;
      *(uint4*)&Bsl[aw0 + 64 * BK] = nb1;
      if (st2) *(uint4*)&Bsl[aw0 + 128 * BK] = nb2;
      __syncthreads();
    }
  }

#pragma unroll
  for (int i = 0; i < 4; ++i) {
    int gr0 = row0 + wm * 64 + i * 16 + fs * 4;
    float rs[4];
#pragma unroll
    for (int r = 0; r < 4; ++r) rs[r] = rowscale ? rowscale[gr0 + r] : 1.f;
#pragma unroll
    for (int j = 0; j < 5; ++j) {
      int gc = col0 + wn * 80 + j * 16 + fr;
      if (gc < DP) {
        float cb = (colbias && gc < DIM) ? colbias[gc] : 0.f;
#pragma unroll
        for (int r = 0; r < 4; ++r) {
          u16 o = (gc < DIM) ? f2bf(fmaf(acc[i][j][r], rs[r], cb)) : (u16)0;
          C[(size_t)(gr0 + r) * DP + gc] = o;
        }
      }
    }
  }
}

// ---------------- SpMM aggregate + fused BN-stat partials ----------------
// v3: block stages its srcs slice + indptr slice into LDS (kills the per-batch
// index round-trip); each wave processes its 16 nodes as 8 interleaved PAIRS
// (v, v+8) with predicated zero-row padding -> 8-16 independent gathers in
// flight per lane, branch-free inner body.

__launch_bounds__(256)
__global__ void spmm_kernel(const u16* __restrict__ X, u16* __restrict__ Y,
                            const int* __restrict__ indptr, const int* __restrict__ srcs,
                            const float* __restrict__ dinv, const float* __restrict__ bias,
                            float* __restrict__ bn_sum, float* __restrict__ bn_sq) {
  __shared__ float ls[DP], lq[DP];
  __shared__ int sptr[65];
  __shared__ int sidx[LDSE];
  int tid = threadIdx.x;
  for (int i = tid; i < DP; i += 256) { ls[i] = 0.f; lq[i] = 0.f; }
  int vb = blockIdx.x * 64;
  if (tid < 65) sptr[tid] = indptr[vb + tid];
  __syncthreads();
  int ebase = sptr[0];
  int ecnt = sptr[64] - ebase;
  const int* ip;   // generic pointer: LDS fast path, global fallback
  if (ecnt <= LDSE) {
    for (int i = tid; i < ecnt; i += 256) sidx[i] = srcs[ebase + i];
    ip = sidx;
  } else {
    ip = srcs + ebase;
  }
  __syncthreads();

  int lane = tid & 63, wv = tid >> 6;
  int c0 = lane << 2;
  int c1 = 256 + (lane << 2);
  bool tl = lane < 8;
  float bia[4], bib[4];
#pragma unroll
  for (int j = 0; j < 4; ++j) bia[j] = bias[c0 + j];
#pragma unroll
  for (int j = 0; j < 4; ++j) bib[j] = (tl && c1 + j < DIM) ? bias[c1 + j] : 0.f;
  float s0[4] = {}, q0[4] = {}, s1[4] = {}, q1[4] = {};

  for (int g = 0; g < 8; ++g) {
    int nA = wv * 16 + g;      // local node ids within block
    int nB = nA + 8;
    int ebA = sptr[nA] - ebase, neA = sptr[nA + 1] - sptr[nA];
    int ebB = sptr[nB] - ebase, neB = sptr[nB + 1] - sptr[nB];
    int nemax = neA > neB ? neA : neB;
    const u16* xA = X + (size_t)(vb + nA) * DP;
    const u16* xB = X + (size_t)(vb + nB) * DP;
    uint2 mA = *(const uint2*)(xA + c0);
    uint2 mB = *(const uint2*)(xB + c0);
    uint2 tA, tB;
    if (tl) { tA = *(const uint2*)(xA + c1); tB = *(const uint2*)(xB + c1); }
    float A0[4] = {}, B0[4] = {}, A1[4] = {}, B1[4] = {};
    acc4(A0, mA); acc4(B0, mB);
    if (tl) { acc4(A1, tA); acc4(B1, tB); }

    for (int e = 0; e < nemax; e += 4) {
      bool aA = e < neA, aB = e < neB;   // padded degs are multiples of 4
      int oA = aA ? ebA + e : 0;
      int oB = aB ? ebB + e : 0;
      int ia[4], ib[4];
#pragma unroll
      for (int j = 0; j < 4; ++j) {
        int va = ip[oA + j], vbx = ip[oB + j];
        ia[j] = aA ? va : NN;
        ib[j] = aB ? vbx : NN;
      }
      const u16* pa[4]; const u16* pb[4];
#pragma unroll
      for (int j = 0; j < 4; ++j) {
        pa[j] = X + (size_t)ia[j] * DP;
        pb[j] = X + (size_t)ib[j] * DP;
      }
      uint2 ma[4], mb[4];
#pragma unroll
      for (int j = 0; j < 4; ++j) ma[j] = *(const uint2*)(pa[j] + c0);
#pragma unroll
      for (int j = 0; j < 4; ++j) mb[j] = *(const uint2*)(pb[j] + c0);
      uint2 ta[4], tb[4];
      if (tl) {
#pragma unroll
        for (int j = 0; j < 4; ++j) ta[j] = *(const uint2*)(pa[j] + c1);
#pragma unroll
        for (int j = 0; j < 4; ++j) tb[j] = *(const uint2*)(pb[j] + c1);
      }
#pragma unroll
      for (int j = 0; j < 4; ++j) { acc4(A0, ma[j]); acc4(B0, mb[j]); }
      if (tl) {
#pragma unroll
        for (int j = 0; j < 4; ++j) { acc4(A1, ta[j]); acc4(B1, tb[j]); }
      }
    }

    float dvA = dinv[vb + nA], dvB = dinv[vb + nB];
    u16* yA = Y + (size_t)(vb + nA) * DP;
    u16* yB = Y + (size_t)(vb + nB) * DP;
    float ya[4], yb[4];
#pragma unroll
    for (int j = 0; j < 4; ++j) {
      ya[j] = fmaf(dvA, A0[j], bia[j]);
      s0[j] += ya[j]; q0[j] += ya[j] * ya[j];
      yb[j] = fmaf(dvB, B0[j], bia[j]);
      s0[j] += yb[j]; q0[j] += yb[j] * yb[j];
    }
    uint2 wa, wb;
    wa.x = (unsigned)f2bf(ya[0]) | ((unsigned)f2bf(ya[1]) << 16);
    wa.y = (unsigned)f2bf(ya[2]) | ((unsigned)f2bf(ya[3]) << 16);
    wb.x = (unsigned)f2bf(yb[0]) | ((unsigned)f2bf(yb[1]) << 16);
    wb.y = (unsigned)f2bf(yb[2]) | ((unsigned)f2bf(yb[3]) << 16);
    *(uint2*)(yA + c0) = wa;
    *(uint2*)(yB + c0) = wb;
    if (tl) {
      float za[4], zb[4];
#pragma unroll
      for (int j = 0; j < 4; ++j) {
        za[j] = fmaf(dvA, A1[j], bib[j]);
        s1[j] += za[j]; q1[j] += za[j] * za[j];
        zb[j] = fmaf(dvB, B1[j], bib[j]);
        s1[j] += zb[j]; q1[j] += zb[j] * zb[j];
      }
      uint2 ua, ub;
      ua.x = (unsigned)f2bf(za[0]) | ((unsigned)f2bf(za[1]) << 16);
      ua.y = (unsigned)f2bf(za[2]) | ((unsigned)f2bf(za[3]) << 16);
      ub.x = (unsigned)f2bf(zb[0]) | ((unsigned)f2bf(zb[1]) << 16);
      ub.y = (unsigned)f2bf(zb[2]) | ((unsigned)f2bf(zb[3]) << 16);
      *(uint2*)(yA + c1) = ua;
      *(uint2*)(yB + c1) = ub;
    }
  }

#pragma unroll
  for (int j = 0; j < 4; ++j) { atomicAdd(&ls[c0 + j], s0[j]); atomicAdd(&lq[c0 + j], q0[j]); }
  if (tl) {
#pragma unroll
    for (int j = 0; j < 4; ++j) { atomicAdd(&ls[c1 + j], s1[j]); atomicAdd(&lq[c1 + j], q1[j]); }
  }
  __syncthreads();
  for (int i = tid; i < DP; i += 256) {
    atomicAdd(&bn_sum[i], ls[i]);
    atomicAdd(&bn_sq[i], lq[i]);
  }
}

__global__ void bn_finalize_kernel(const float* __restrict__ bn_sum, const float* __restrict__ bn_sq,
                                   const float* __restrict__ gamma, const float* __restrict__ beta,
                                   float* __restrict__ scale, float* __restrict__ shift) {
  int d = threadIdx.x;
  if (d >= DP) return;
  if (d < DIM) {
    const float invN = 1.0f / (float)NN;
    float mu = bn_sum[d] * invN;
    float var = bn_sq[d] * invN - mu * mu;
    float rstd = rsqrtf(var + BN_EPS);
    float sc = gamma[d] * rstd;
    scale[d] = sc;
    shift[d] = fmaf(-mu, sc, beta[d]);
  } else {
    scale[d] = 0.f;
    shift[d] = 0.f;
  }
}

// ---------------- MFMA Gram decode ----------------

__launch_bounds__(256)
__global__ void decode_kernel(const u16* __restrict__ H, float* __restrict__ out) {
  __shared__ __align__(16) u16 tile[4][2][NPG * BK];
  int tid = threadIdx.x, lane = tid & 63, wv = tid >> 6;
  int g = blockIdx.x * 4 + wv;
  const u16* Hg = H + (size_t)g * NPG * DP;
  const int ssl = lane & 3;
  int soff[4];
  const u16* sg[4];
#pragma unroll
  for (int i = 0; i < 4; ++i) {
    int r = (lane >> 2) + i * 16;
    soff[i] = r * BK + ((ssl ^ (r & 3) ^ ((r >> 2) & 3)) << 3);
    sg[i] = Hg + (size_t)r * DP + ssl * 8;
  }
  const int fr = lane & 15, fs = lane >> 4;
  const int fswz = ((fs ^ (fr & 3) ^ ((fr >> 2) & 3)) << 3);
  int foff[4];
#pragma unroll
  for (int i = 0; i < 4; ++i) foff[i] = (i * 16 + fr) * BK + fswz;

  u16* t0 = tile[wv][0];
  u16* t1 = tile[wv][1];
  uint4 rg[4];
#pragma unroll
  for (int i = 0; i < 4; ++i) rg[i] = *(const uint4*)(sg[i]);
#pragma unroll
  for (int i = 0; i < 4; ++i) *(uint4*)&t0[soff[i]] = rg[i];

  f32x4 acc[4][4];
#pragma unroll
  for (int i = 0; i < 4; ++i)
#pragma unroll
    for (int j = 0; j < 4; ++j) acc[i][j] = (f32x4){0.f, 0.f, 0.f, 0.f};

  for (int s = 0; s < DP / BK; ++s) {
    u16* cur = (s & 1) ? t1 : t0;
    u16* nxt = (s & 1) ? t0 : t1;
    const bool more = (s < DP / BK - 1);
    if (more) {
#pragma unroll
      for (int i = 0; i < 4; ++i) rg[i] = *(const uint4*)(sg[i] + (s + 1) * BK);
    }
    s16x8 af[4];
#pragma unroll
    for (int i = 0; i < 4; ++i) af[i] = *(const s16x8*)&cur[foff[i]];
#pragma unroll
    for (int i = 0; i < 4; ++i)
#pragma unroll
      for (int j = 0; j < 4; ++j)
        acc[i][j] = __builtin_amdgcn_mfma_f32_16x16x32_bf16(af[i], af[j], acc[i][j], 0, 0, 0);
    if (more) {
#pragma unroll
      for (int i = 0; i < 4; ++i) *(uint4*)&nxt[soff[i]] = rg[i];
    }
  }
  float* og = out + (size_t)g * NPG * NPG;
#pragma unroll
  for (int i = 0; i < 4; ++i) {
    int m0 = i * 16 + fs * 4;
#pragma unroll
    for (int j = 0; j < 4; ++j) {
      int n = j * 16 + fr;
#pragma unroll
      for (int r = 0; r < 4; ++r) og[(m0 + r) * NPG + n] = acc[i][j][r];
    }
  }
}

// ---------------- launch ----------------

extern "C" void kernel_launch(void* const* d_in, const int* in_sizes, int n_in,
                              void* d_out, int out_size, void* d_ws, size_t ws_size,
                              hipStream_t stream) {
  const int* xa = (const int*)d_in[0];
  const int* ei = (const int*)d_in[1];
  const float* emb = (const float*)d_in[2];
  const float* convW = (const float*)d_in[3];
  const float* convB = (const float*)d_in[4];
  const float* gamma = (const float*)d_in[5];
  const float* beta = (const float*)d_in[6];
  const float* postW = (const float*)d_in[7];
  const float* postB = (const float*)d_in[8];
  float* out = (float*)d_out;

  char* w = (char*)d_ws;
  u16* P = (u16*)w;          w += (size_t)(NN + 1) * DP * sizeof(u16);
  u16* Q = (u16*)w;          w += (size_t)(NN + 1) * DP * sizeof(u16);
  u16* Wp = (u16*)w;         w += (size_t)6 * 320 * DP * sizeof(u16);
  float* dinv = (float*)w;   w += (size_t)NN * sizeof(float);
  int* cnt = (int*)w;        w += (size_t)NN * sizeof(int);
  int* cnt_pad = (int*)w;    w += (size_t)NN * sizeof(int);
  int* indptr = (int*)w;     w += (size_t)(NN + 64) * sizeof(int);
  int* cursor = (int*)w;     w += (size_t)NN * sizeof(int);
  int* srcs = (int*)w;       w += (size_t)NEPAD * sizeof(int);
  int* partials = (int*)w;   w += 256 * sizeof(int);
  float* bn_sum = (float*)w; w += DP * sizeof(float);
  float* bn_sq = (float*)w;  w += DP * sizeof(float);
  float* bnscale = (float*)w; w += DP * sizeof(float);
  float* bnshift = (float*)w; w += DP * sizeof(float);

  size_t need = (size_t)(w - (char*)d_ws);
  if (ws_size < need) return;

  hipMemsetAsync(cnt, 0, (size_t)NN * sizeof(int), stream);
  hist_kernel<<<NE / 256, 256, 0, stream>>>(ei, cnt);
  pad_dinv_kernel<<<NN / 256, 256, 0, stream>>>(cnt, cnt_pad, dinv);
  scan_block_kernel<<<NN / 1024, 1024, 0, stream>>>(cnt_pad, indptr, partials);
  scan_partials_kernel<<<1, 128, 0, stream>>>(partials);
  add_offsets_kernel<<<NN / 256, 256, 0, stream>>>(indptr, partials, cursor, cnt_pad);
  fill_csr_kernel<<<NE / 256, 256, 0, stream>>>(ei, cursor, srcs);
  pad_fill_kernel<<<NN / 256, 256, 0, stream>>>(cursor, indptr, srcs);
  wpad_kernel<<<(6 * 320 * DP + 255) / 256, 256, 0, stream>>>(convW, postW, Wp);
  embed_kernel<<<NN, 128, 0, stream>>>(xa, emb, P);
  zrow_kernel<<<1, 288, 0, stream>>>(P, Q);

  for (int l = 0; l < NLAY; ++l) {
    gemm_kernel<<<(NN / BM) * 2, 256, 0, stream>>>(
        P, Wp + (size_t)l * 320 * DP, Q,
        l ? bnscale : nullptr, l ? bnshift : nullptr, dinv, nullptr);
    hipMemsetAsync(bn_sum, 0, 2 * DP * sizeof(float), stream);
    spmm_kernel<<<NN / 64, 256, 0, stream>>>(Q, P, indptr, srcs, dinv,
                                             convB + (size_t)l * DIM, bn_sum, bn_sq);
    bn_finalize_kernel<<<1, DP, 0, stream>>>(bn_sum, bn_sq, gamma + (size_t)l * DIM,
                                             beta + (size_t)l * DIM, bnscale, bnshift);
  }

  gemm_kernel<<<(NN / BM) * 2, 256, 0, stream>>>(
      P, Wp + (size_t)5 * 320 * DP, Q, bnscale, bnshift, nullptr, postB);

  decode_kernel<<<NGRAPH / 4, 256, 0, stream>>>(Q, out);
}